// Round 5
// baseline (519.444 us; speedup 1.0000x reference)
//
#include <hip/hip_runtime.h>
#include <math.h>

#define B 4
#define S 2048
#define D 1024
#define H 16
#define DK 64
#define MS (B * S)   // 8192
#define GKA 2048     // split storage width: [hi | lo]

typedef short bf16x8 __attribute__((ext_vector_type(8)));
typedef float f32x4 __attribute__((ext_vector_type(4)));

__device__ __forceinline__ unsigned short f2bf(float x) {
  union { float f; unsigned u; } v; v.f = x;
  unsigned r = v.u + 0x7fff + ((v.u >> 16) & 1);  // RNE
  return (unsigned short)(r >> 16);
}
__device__ __forceinline__ float bf2f(unsigned short h) {
  union { unsigned u; float f; } v; v.u = ((unsigned)h) << 16;
  return v.f;
}
__device__ __forceinline__ void split2(float x, unsigned short& hi, unsigned short& lo) {
  hi = f2bf(x);
  lo = f2bf(x - bf2f(hi));
}

// ---------------------------------------------------------------------------
// prep: ALL input preprocessing in one launch, chunked by blockIdx.x:
//  [0,24576)      split k,v,q -> KSP,VSP,QSP  [8192][2048] ([hi|lo])
//  [24576,32768)  split wk,wv -> WKS,WVS      [1024][2048] (B^T layout)
//  [32768,36864)  split wq    -> WQA [16][1024][128] (A layout, [hi|lo] along k)
//  [36864,37888)  cast wo     -> WOB [1024][1024] plain bf16 (B^T layout)
//  [37888,38144)  zero M
// ---------------------------------------------------------------------------
__global__ __launch_bounds__(256) void prep_kernel(
    const float* __restrict__ q, const float* __restrict__ k, const float* __restrict__ v,
    const float* __restrict__ wk, const float* __restrict__ wv, const float* __restrict__ wq,
    const float* __restrict__ wo,
    unsigned short* __restrict__ KSP, unsigned short* __restrict__ VSP,
    unsigned short* __restrict__ QSP,
    unsigned short* __restrict__ WKS, unsigned short* __restrict__ WVS,
    unsigned short* __restrict__ WQA, unsigned short* __restrict__ WOB,
    float* __restrict__ M) {
  const int blk = blockIdx.x;
  const int tid = threadIdx.x;
  if (blk < 24576) {  // activation splits
    const int which = blk >> 13;
    const int bb = blk & 8191;
    const float* X = which == 0 ? k : (which == 1 ? v : q);
    unsigned short* O = which == 0 ? KSP : (which == 1 ? VSP : QSP);
    int t = bb * 256 + tid;
    int idx = t * 4;
    int m = idx >> 10, d = idx & 1023;
    float4 x = *(const float4*)&X[idx];
    union { unsigned short h[4]; ushort4 u; } uh, ul;
    split2(x.x, uh.h[0], ul.h[0]);
    split2(x.y, uh.h[1], ul.h[1]);
    split2(x.z, uh.h[2], ul.h[2]);
    split2(x.w, uh.h[3], ul.h[3]);
    *(ushort4*)&O[(size_t)m * GKA + d] = uh.u;
    *(ushort4*)&O[(size_t)m * GKA + 1024 + d] = ul.u;
  } else if (blk < 32768) {  // wk/wv splits (B^T layout)
    const int which = (blk - 24576) >> 12;
    const int bb = (blk - 24576) & 4095;
    const float* W = which == 0 ? wk : wv;
    unsigned short* O = which == 0 ? WKS : WVS;
    int t = bb * 256 + tid;
    int d = t & 1023, n = t >> 10;
    int h = n >> 6, dk = n & 63;
    float x = W[((size_t)(h << 10) + d) * 64 + dk];
    unsigned short hi, lo;
    split2(x, hi, lo);
    size_t ro = (size_t)n * GKA + d;
    O[ro] = hi;
    O[ro + 1024] = lo;
  } else if (blk < 36864) {  // wq split (A layout: [h][d][hi 64|lo 64])
    int t = (blk - 32768) * 256 + tid;  // 1M = 16*1024*64
    int kk = t & 63;
    int hd = t >> 6;  // h*1024 + d
    float x = wq[t];
    unsigned short hi, lo;
    split2(x, hi, lo);
    WQA[(size_t)hd * 128 + kk] = hi;
    WQA[(size_t)hd * 128 + 64 + kk] = lo;
  } else if (blk < 37888) {  // wo cast
    int t = (blk - 36864) * 256 + tid;
    int idx = t * 4;
    float4 x = *(const float4*)&wo[idx];
    ushort4 u;
    u.x = f2bf(x.x); u.y = f2bf(x.y); u.z = f2bf(x.z); u.w = f2bf(x.w);
    *(ushort4*)&WOB[idx] = u;
  } else {  // zero M (256 blocks * 256 threads * 4 = 262144 floats)
    int t = (blk - 37888) * 256 + tid;
    *(float4*)&M[(size_t)t * 4] = (float4){0.f, 0.f, 0.f, 0.f};
  }
}

// ---------------------------------------------------------------------------
// gemm256: templated 256xBN-tile 8-wave GEMM core, phase-level A-prefetch.
// NWC: waves along N (4 -> BN=256, 2 -> BN=128). NWR = 8/NWC waves along M.
// EPI: 0 = fp32 + bias store; 1 = per-head softmax -> bf16;
//      2 = TRANSPOSED split-bf16 store T[d][hi 8192 s | lo 8192 s] (for M).
// KLOG: 3072 (Markidis 3-term split, stride 2048, wrap) or 1024 (plain bf16).
// Core schedule identical to the verified round-4 kernel (112 VGPR, no spill).
// ---------------------------------------------------------------------------
__device__ __forceinline__ void gll(const unsigned short* g, unsigned short* l) {
  __builtin_amdgcn_global_load_lds((const __attribute__((address_space(1))) void*)g,
                                   (__attribute__((address_space(3))) void*)l, 16, 0, 0);
}

template <int NWC>
__device__ __forceinline__ void stageT(
    const unsigned short* __restrict__ A, const unsigned short* __restrict__ BT,
    const unsigned* aoffs, const unsigned* boffs,
    unsigned short* Asb, unsigned short* Bsb, int aof, int bof, int w) {
#pragma unroll
  for (int g = 0; g < 4; ++g) gll(A + aoffs[g] + aof, Asb + g * 4096 + w * 512);
#pragma unroll
  for (int g = 0; g < NWC; ++g) gll(BT + boffs[g] + bof, Bsb + g * 4096 + w * 512);
}

template <int NWC, int EPI, int KLOG>
__global__ __launch_bounds__(512, 2) void gemm256(
    const unsigned short* __restrict__ A0, const unsigned short* __restrict__ A1,
    const unsigned short* __restrict__ Bt0, const unsigned short* __restrict__ Bt1,
    const float* __restrict__ bias0, const float* __restrict__ bias1,
    void* __restrict__ C0, void* __restrict__ C1) {
  constexpr int NWR = 8 / NWC;          // waves along M
  constexpr int MR = (256 / NWR) / 16;  // A-frags per wave (8 or 4)
  constexpr int NPH = MR / 2;           // phases per tile (4 or 2)
  constexpr int BN = NWC * 64;          // tile N
  constexpr int AST = (KLOG == 1024) ? 1024 : 2048;
  constexpr int NKT = KLOG / 64;        // K-tiles

  __shared__ __align__(16) unsigned short As[2][256 * 64];
  __shared__ __align__(16) unsigned short Bs[2][BN * 64];

  const int tid = threadIdx.x;
  const int lane = tid & 63;
  const int w = tid >> 6;
  const int wr = w / NWC;
  const int wc = w % NWC;
  const int fm = lane & 15;
  const int quad = lane >> 4;
  const int sx = (fm & 7) << 3;
  const size_t bm = (size_t)blockIdx.y * 256;
  const size_t bn = (size_t)blockIdx.x * BN;

  const unsigned short* A;
  const unsigned short* BT;
  const float* bias;
  if constexpr (EPI == 1) {
    const int b = blockIdx.y >> 3;  // 2048 rows per batch / 256-row tiles
    A = A0;
    BT = Bt0 + (size_t)b * D * GKA;
    bias = bias0 + (size_t)b * D;
  } else {
    A = blockIdx.z ? A1 : A0;
    BT = blockIdx.z ? Bt1 : Bt0;
    bias = blockIdx.z ? bias1 : bias0;
  }

  // staging source offsets (col pre-swizzled -> linear LDS dest = swizzled tile)
  const int srow = tid >> 3;                        // 0..63 within 64-row group
  const int scol = ((tid & 7) ^ (srow & 7)) << 3;   // swizzled col (ushorts)
  unsigned aoffs[4], boffs[NWC];
#pragma unroll
  for (int g = 0; g < 4; ++g) aoffs[g] = (unsigned)((bm + g * 64 + srow) * AST + scol);
#pragma unroll
  for (int g = 0; g < NWC; ++g) boffs[g] = (unsigned)((bn + g * 64 + srow) * AST + scol);

  // read-side bases: low-6-bit field (kk*32 + quad*8) ^ sx; rows add >=bit6.
  const int basek0 = (quad * 8) ^ sx;
  const int basek1 = (32 + quad * 8) ^ sx;
  const int arow0 = (wr * (MR * 16) + fm) * 64;
  const int brow0 = (wc * 64 + fm) * 64;

  f32x4 acc[MR][4];
#pragma unroll
  for (int i = 0; i < MR; ++i)
#pragma unroll
    for (int j = 0; j < 4; ++j) acc[i][j] = (f32x4){0.f, 0.f, 0.f, 0.f};

  auto ka = [](int k0) { return (KLOG == 3072) ? (k0 < 2048 ? k0 : k0 - 2048) : k0; };
  auto kb = [](int k0) { return (KLOG == 3072) ? (k0 < 1024 ? k0 : k0 - 1024) : k0; };

  // prologue: tiles 0 and 1 in flight
  stageT<NWC>(A, BT, aoffs, boffs, As[0], Bs[0], ka(0), kb(0), w);
  stageT<NWC>(A, BT, aoffs, boffs, As[1], Bs[1], ka(64), kb(64), w);

#pragma unroll 1
  for (int t = 0; t < NKT; ++t) {
    const unsigned short* Ab = As[t & 1];
    const unsigned short* Bb = Bs[t & 1];
    unsigned short* Asb = As[t & 1];
    unsigned short* Bsb = Bs[t & 1];

    if (t < NKT - 1) {
      if constexpr (NWC == 4) asm volatile("s_waitcnt vmcnt(8)" ::: "memory");
      else                    asm volatile("s_waitcnt vmcnt(6)" ::: "memory");
    } else {
      asm volatile("s_waitcnt vmcnt(0)" ::: "memory");
    }
    __builtin_amdgcn_s_barrier();       // B0: tile t visible to all waves
    __builtin_amdgcn_sched_barrier(0);

    bf16x8 bfr[4][2];
    bf16x8 afr[2][2][2];  // [phase parity][row][kk]

    // initial reads: all B-frags + phase-0 A-frags (12 ds_read_b128)
#pragma unroll
    for (int j = 0; j < 4; ++j) {
      bfr[j][0] = *(const bf16x8*)&Bb[brow0 + j * 1024 + basek0];
      bfr[j][1] = *(const bf16x8*)&Bb[brow0 + j * 1024 + basek1];
    }
#pragma unroll
    for (int ii = 0; ii < 2; ++ii) {
      afr[0][ii][0] = *(const bf16x8*)&Ab[arow0 + ii * 1024 + basek0];
      afr[0][ii][1] = *(const bf16x8*)&Ab[arow0 + ii * 1024 + basek1];
    }
    __builtin_amdgcn_sched_barrier(0);

#pragma unroll
    for (int qq = 0; qq < NPH; ++qq) {
      if (qq + 1 < NPH) {
        // prefetch next phase's A-frags; they drain under this phase's MFMAs
#pragma unroll
        for (int ii = 0; ii < 2; ++ii) {
          afr[(qq + 1) & 1][ii][0] =
              *(const bf16x8*)&Ab[arow0 + ((qq + 1) * 2 + ii) * 1024 + basek0];
          afr[(qq + 1) & 1][ii][1] =
              *(const bf16x8*)&Ab[arow0 + ((qq + 1) * 2 + ii) * 1024 + basek1];
        }
        asm volatile("s_waitcnt lgkmcnt(4)" ::: "memory");  // current phase ready
      } else {
        asm volatile("s_waitcnt lgkmcnt(0)" ::: "memory");  // last phase: drain
      }
      __builtin_amdgcn_sched_barrier(0);  // rule #18: pin MFMA below the wait
      __builtin_amdgcn_s_setprio(1);
#pragma unroll
      for (int ii = 0; ii < 2; ++ii)
#pragma unroll
        for (int j = 0; j < 4; ++j) {
          acc[qq * 2 + ii][j] = __builtin_amdgcn_mfma_f32_16x16x32_bf16(
              afr[qq & 1][ii][0], bfr[j][0], acc[qq * 2 + ii][j], 0, 0, 0);
          acc[qq * 2 + ii][j] = __builtin_amdgcn_mfma_f32_16x16x32_bf16(
              afr[qq & 1][ii][1], bfr[j][1], acc[qq * 2 + ii][j], 0, 0, 0);
        }
      __builtin_amdgcn_s_setprio(0);
      __builtin_amdgcn_sched_barrier(0);
    }

    __builtin_amdgcn_s_barrier();       // B1: all waves done reading buf
    if (t + 2 < NKT) {
      const int k0 = (t + 2) * 64;
      stageT<NWC>(A, BT, aoffs, boffs, Asb, Bsb, ka(k0), kb(k0), w);
    }
  }

  if constexpr (EPI == 0) {
    float* C = (float*)(blockIdx.z ? C1 : C0);
#pragma unroll
    for (int i = 0; i < MR; ++i)
#pragma unroll
      for (int j = 0; j < 4; ++j) {
        size_t row = bm + wr * (MR * 16) + i * 16 + quad * 4;
        size_t col = bn + wc * 64 + j * 16 + fm;
        float bb = bias[col];
#pragma unroll
        for (int r = 0; r < 4; ++r) C[(row + r) * D + col] = acc[i][j][r] + bb;
      }
  } else if constexpr (EPI == 2) {
    // transposed split-bf16 store: T[d][hi 8192 s | lo 8192 s]
    unsigned short* T = (unsigned short*)(blockIdx.z ? C1 : C0);
#pragma unroll
    for (int i = 0; i < MR; ++i)
#pragma unroll
      for (int j = 0; j < 4; ++j) {
        size_t row = bm + wr * (MR * 16) + i * 16 + quad * 4;  // s
        size_t col = bn + wc * 64 + j * 16 + fm;               // d
        float bb = bias[col];
        ushort4 hv, lv;
        unsigned short hh, ll;
        split2(acc[i][j][0] + bb, hh, ll); hv.x = hh; lv.x = ll;
        split2(acc[i][j][1] + bb, hh, ll); hv.y = hh; lv.y = ll;
        split2(acc[i][j][2] + bb, hh, ll); hv.z = hh; lv.z = ll;
        split2(acc[i][j][3] + bb, hh, ll); hv.w = hh; lv.w = ll;
        size_t base = col * 16384 + row;
        *(ushort4*)&T[base] = hv;
        *(ushort4*)&T[base + 8192] = lv;
      }
  } else {
    // softmax over this wave's 64 cols (= one full head), bf16 out
    unsigned short* HB = (unsigned short*)C0;
    const size_t head_col0 = bn + wc * 64;
    float bj[4];
#pragma unroll
    for (int j = 0; j < 4; ++j) bj[j] = bias[head_col0 + j * 16 + fm];
#pragma unroll
    for (int i = 0; i < MR; ++i) {
      f32x4 val[4];
#pragma unroll
      for (int j = 0; j < 4; ++j)
#pragma unroll
        for (int r = 0; r < 4; ++r) val[j][r] = (acc[i][j][r] + bj[j]) * 0.125f;

      f32x4 mx = val[0];
#pragma unroll
      for (int j = 1; j < 4; ++j)
#pragma unroll
        for (int r = 0; r < 4; ++r) mx[r] = fmaxf(mx[r], val[j][r]);
#pragma unroll
      for (int off = 1; off < 16; off <<= 1)
#pragma unroll
        for (int r = 0; r < 4; ++r) mx[r] = fmaxf(mx[r], __shfl_xor(mx[r], off, 64));

      f32x4 e[4];
      f32x4 sm = (f32x4){0.f, 0.f, 0.f, 0.f};
#pragma unroll
      for (int j = 0; j < 4; ++j)
#pragma unroll
        for (int r = 0; r < 4; ++r) {
          e[j][r] = __expf(val[j][r] - mx[r]);
          sm[r] += e[j][r];
        }
#pragma unroll
      for (int off = 1; off < 16; off <<= 1)
#pragma unroll
        for (int r = 0; r < 4; ++r) sm[r] += __shfl_xor(sm[r], off, 64);

      f32x4 inv;
#pragma unroll
      for (int r = 0; r < 4; ++r) inv[r] = 1.0f / sm[r];

#pragma unroll
      for (int j = 0; j < 4; ++j)
#pragma unroll
        for (int r = 0; r < 4; ++r) {
          size_t row = bm + wr * (MR * 16) + i * 16 + quad * 4 + r;
          HB[row * D + head_col0 + j * 16 + fm] = f2bf(e[j][r] * inv[r]);
        }
    }
  }
}

// ---------------------------------------------------------------------------
// compute_m_mfma: M[b,h] += KHT_slice^T-free MFMA GEMM.
// KHT/VHT: [1024 d][hi 8192 s | lo 8192 s] split bf16 (written by EPI=2).
// M[b,h][i][j] = sum_s KH[s,i]*VH[s,j]  ->  A=KHT rows i, B=VHT rows j, K=s.
// grid (8 s-chunks, 64 bh), 256 thr = 4 waves; each wave owns a 64-s
// sub-window x 3 Markidis terms (6 k-steps of 32); LDS cross-wave reduce,
// then fp32 atomicAdd into M (zeroed by prep).
// LDS tiles [64 rows][hi 256 | lo 256] with the XOR swizzle (conflict-free).
// ---------------------------------------------------------------------------
__global__ __launch_bounds__(256) void compute_m_mfma(
    const unsigned short* __restrict__ KHT, const unsigned short* __restrict__ VHT,
    float* __restrict__ Mout) {
  const int sc = blockIdx.x;
  const int bh = blockIdx.y;
  const int h = bh & 15, b = bh >> 4;
  const int tid = threadIdx.x;
  const int lane = tid & 63;
  const int w = tid >> 6;
  const int fm = lane & 15;
  const int quad = lane >> 4;

  __shared__ __align__(16) unsigned short Ka[64 * 512];  // 64 KiB
  __shared__ __align__(16) unsigned short Va[64 * 512];  // 64 KiB

  const int S0 = b * 2048 + sc * 256;
  const int rsub = tid >> 6;     // 0..3
  const int chunk = tid & 63;
  // stage both matrices: 16 rounds x 4 rows; source col pre-swizzled so the
  // linear global_load_lds dest equals the swizzled LDS tile.
#pragma unroll
  for (int g = 0; g < 16; ++g) {
    const int row = g * 4 + rsub;
    const int cp = (chunk ^ (row & 7)) << 3;  // swizzled col (ushorts), 0..511
    const size_t gc = (cp < 256) ? (size_t)(S0 + cp) : (size_t)(8192 + S0 + (cp - 256));
    const size_t gaddr = ((size_t)(h * 64 + row)) * 16384 + gc;
    gll(KHT + gaddr, Ka + g * 2048 + tid * 8);
    gll(VHT + gaddr, Va + g * 2048 + tid * 8);
  }
  asm volatile("s_waitcnt vmcnt(0)" ::: "memory");
  __builtin_amdgcn_s_barrier();

  f32x4 acc[4][4];
#pragma unroll
  for (int i = 0; i < 4; ++i)
#pragma unroll
    for (int j = 0; j < 4; ++j) acc[i][j] = (f32x4){0.f, 0.f, 0.f, 0.f};

  const int ws = w * 64;          // this wave's 64-s sub-window
  const int sxr = (fm & 7) << 3;  // read swizzle (row&7 == fm&7 for rows f*16+fm)
#pragma unroll
  for (int T = 0; T < 3; ++T) {
    const int ca = (T == 1 ? 256 : 0) + ws;  // A: hi, lo, hi
    const int cb = (T == 2 ? 256 : 0) + ws;  // B: hi, hi, lo
#pragma unroll
    for (int kk = 0; kk < 2; ++kk) {
      bf16x8 af[4], bf[4];
#pragma unroll
      for (int f = 0; f < 4; ++f) {
        af[f] = *(const bf16x8*)&Ka[(f * 16 + fm) * 512 + ((ca + kk * 32 + quad * 8) ^ sxr)];
        bf[f] = *(const bf16x8*)&Va[(f * 16 + fm) * 512 + ((cb + kk * 32 + quad * 8) ^ sxr)];
      }
#pragma unroll
      for (int i = 0; i < 4; ++i)
#pragma unroll
        for (int j = 0; j < 4; ++j)
          acc[i][j] = __builtin_amdgcn_mfma_f32_16x16x32_bf16(af[i], bf[j], acc[i][j], 0, 0, 0);
    }
  }

  // cross-wave reduce via LDS (reuse Ka: 4 x 4096 f32 = 64 KiB), then atomics
  __syncthreads();
  float* Ws = (float*)Ka;
  float* Wp = Ws + w * 4096;
#pragma unroll
  for (int i = 0; i < 4; ++i)
#pragma unroll
    for (int j = 0; j < 4; ++j)
#pragma unroll
      for (int r = 0; r < 4; ++r)
        Wp[(i * 16 + quad * 4 + r) * 64 + j * 16 + fm] = acc[i][j][r];
  __syncthreads();

  float* Mp = Mout + (size_t)bh * 4096;
#pragma unroll
  for (int u = 0; u < 4; ++u) {
    const int e = tid * 16 + u * 4;
    f32x4 s0 = *(f32x4*)&Ws[e];
    f32x4 s1 = *(f32x4*)&Ws[4096 + e];
    f32x4 s2 = *(f32x4*)&Ws[8192 + e];
    f32x4 s3 = *(f32x4*)&Ws[12288 + e];
#pragma unroll
    for (int r = 0; r < 4; ++r) atomicAdd(&Mp[e + r], s0[r] + s1[r] + s2[r] + s3[r]);
  }
}

// ---------------------------------------------------------------------------
// split_m_bias: M fp32 [bh][64k][64n] -> MSP bf16 [bh][2][64n][64k] (transposed
// hi,lo) AND BQM[bh][64 j] = sum_k bq[h,k]*M[k,j]  (unscaled).
// ---------------------------------------------------------------------------
__global__ __launch_bounds__(256) void split_m_bias_kernel(
    const float* __restrict__ M, const float* __restrict__ bq,
    unsigned short* __restrict__ MSP, float* __restrict__ BQM) {
  const int bh = blockIdx.x;
  const int h = bh & 15;
  const float* Mp = M + (size_t)bh * 4096;
  unsigned short* hiP = MSP + (size_t)bh * 8192;
  unsigned short* loP = hiP + 4096;
  for (int idx = threadIdx.x; idx < 4096; idx += 256) {
    int kk = idx >> 6, nn = idx & 63;
    unsigned short hi, lo;
    split2(Mp[idx], hi, lo);
    hiP[nn * 64 + kk] = hi;
    loP[nn * 64 + kk] = lo;
  }
  if (threadIdx.x < 64) {
    int j = threadIdx.x;
    float a = 0.f;
#pragma unroll 8
    for (int kk = 0; kk < 64; kk++) a += bq[h * 64 + kk] * Mp[kk * 64 + j];
    BQM[(size_t)bh * 64 + j] = a;
  }
}

// ---------------------------------------------------------------------------
// wqm: Wq'[b,h] = Wq[h] @ M[b,h]  (1024x64 per pair), 3-term split MFMA.
// A = WQA [h][1024 d][hi64|lo64]; B = MSP [bh][2][64 n][64 k] (transposed).
// Output WQM [b][n=h*64+j][d hi | 1024+d lo] (B^T layout for the qsm GEMM).
// grid (16, H, B); block = 64 d-rows; wave w owns d-rows [c*64+w*16, +16).
// ---------------------------------------------------------------------------
__global__ __launch_bounds__(256) void wqm_kernel(
    const unsigned short* __restrict__ WQA, const unsigned short* __restrict__ MSP,
    unsigned short* __restrict__ WQM) {
  const int c = blockIdx.x, h = blockIdx.y, b = blockIdx.z;
  const int tid = threadIdx.x;
  const int lane = tid & 63;
  const int w = tid >> 6;
  const int fm = lane & 15;
  const int quad = lane >> 4;
  const int ko = quad * 8;
  const int dbase = c * 64 + w * 16;

  const unsigned short* arow = WQA + ((size_t)h * 1024 + dbase + fm) * 128;
  bf16x8 ahi0 = *(const bf16x8*)&arow[ko];        // k 0..31 hi
  bf16x8 ahi1 = *(const bf16x8*)&arow[32 + ko];   // k 32..63 hi
  bf16x8 alo0 = *(const bf16x8*)&arow[64 + ko];   // k 0..31 lo
  bf16x8 alo1 = *(const bf16x8*)&arow[96 + ko];   // k 32..63 lo

  const unsigned short* hiP = MSP + ((size_t)(b * H + h)) * 8192;
  const unsigned short* loP = hiP + 4096;
  f32x4 acc[4];
#pragma unroll
  for (int j = 0; j < 4; j++) acc[j] = (f32x4){0.f, 0.f, 0.f, 0.f};
#pragma unroll
  for (int j = 0; j < 4; j++) {
    bf16x8 bhi0 = *(const bf16x8*)&hiP[(j * 16 + fm) * 64 + ko];
    bf16x8 bhi1 = *(const bf16x8*)&hiP[(j * 16 + fm) * 64 + 32 + ko];
    bf16x8 blo0 = *(const bf16x8*)&loP[(j * 16 + fm) * 64 + ko];
    bf16x8 blo1 = *(const bf16x8*)&loP[(j * 16 + fm) * 64 + 32 + ko];
    acc[j] = __builtin_amdgcn_mfma_f32_16x16x32_bf16(ahi0, bhi0, acc[j], 0, 0, 0);
    acc[j] = __builtin_amdgcn_mfma_f32_16x16x32_bf16(ahi1, bhi1, acc[j], 0, 0, 0);
    acc[j] = __builtin_amdgcn_mfma_f32_16x16x32_bf16(alo0, bhi0, acc[j], 0, 0, 0);
    acc[j] = __builtin_amdgcn_mfma_f32_16x16x32_bf16(alo1, bhi1, acc[j], 0, 0, 0);
    acc[j] = __builtin_amdgcn_mfma_f32_16x16x32_bf16(ahi0, blo0, acc[j], 0, 0, 0);
    acc[j] = __builtin_amdgcn_mfma_f32_16x16x32_bf16(ahi1, blo1, acc[j], 0, 0, 0);
  }

  // C[d=dbase+quad*4+r][col j*16+fm]; write split to WQM[b][h*64+col][d]
#pragma unroll
  for (int j = 0; j < 4; j++) {
    int n = h * 64 + j * 16 + fm;
    ushort4 hv, lv;
    unsigned short hi, lo;
    split2(acc[j][0], hi, lo); hv.x = hi; lv.x = lo;
    split2(acc[j][1], hi, lo); hv.y = hi; lv.y = lo;
    split2(acc[j][2], hi, lo); hv.z = hi; lv.z = lo;
    split2(acc[j][3], hi, lo); hv.w = hi; lv.w = lo;
    size_t base = ((size_t)b * D + n) * GKA + dbase + quad * 4;
    *(ushort4*)&WQM[base] = hv;
    *(ushort4*)&WQM[base + 1024] = lv;
  }
}

// ---------------------------------------------------------------------------
extern "C" void kernel_launch(void* const* d_in, const int* in_sizes, int n_in,
                              void* d_out, int out_size, void* d_ws, size_t ws_size,
                              hipStream_t stream) {
  const float* q = (const float*)d_in[0];
  const float* k = (const float*)d_in[1];
  const float* v = (const float*)d_in[2];
  const float* wq_w = (const float*)d_in[3];
  const float* wq_b = (const float*)d_in[4];
  const float* wk_w = (const float*)d_in[5];
  const float* wk_b = (const float*)d_in[6];
  const float* wv_w = (const float*)d_in[7];
  const float* wv_b = (const float*)d_in[8];
  const float* wo_w = (const float*)d_in[9];
  const float* wo_b = (const float*)d_in[10];
  float* out = (float*)d_out;

  // ws (143 MB): KSP 32 (->HB 16 | WQM 16) | VSP 32 (->MSP 1 + BQM) | QSP 32 |
  //              VHT 32 | M 1 | WKS 4 | WVS 4 | WQA 4 | WOB 2.  KHT lives in d_out.
  unsigned short* KSP = (unsigned short*)d_ws;
  unsigned short* VSP = KSP + (size_t)16 * 1024 * 1024;
  unsigned short* QSP = VSP + (size_t)16 * 1024 * 1024;
  unsigned short* VHT = QSP + (size_t)16 * 1024 * 1024;       // 32 MB split bf16
  float* M = (float*)(VHT + (size_t)16 * 1024 * 1024);
  unsigned short* WKS = (unsigned short*)(M + 256 * 1024);
  unsigned short* WVS = WKS + (size_t)2 * 1024 * 1024;
  unsigned short* WQA = WVS + (size_t)2 * 1024 * 1024;
  unsigned short* WOB = WQA + (size_t)2 * 1024 * 1024;
  // aliases
  unsigned short* KHT = (unsigned short*)out;        // dead after compute_m
  unsigned short* HB = KSP;                          // KSP dead after gemm KV
  unsigned short* WQM = KSP + (size_t)8 * 1024 * 1024;
  unsigned short* MSP = VSP;                         // VSP dead after gemm KV
  float* BQM = (float*)(VSP + 512 * 1024);

  dim3 blk(256);

  prep_kernel<<<38144, blk, 0, stream>>>(q, k, v, wk_w, wv_w, wq_w, wo_w,
                                         KSP, VSP, QSP, WKS, WVS, WQA, WOB, M);
  // K/V projections: 256x256 tiles, split-Markidis K=3072, transposed split out
  gemm256<4, 2, 3072><<<dim3(4, 32, 2), dim3(512), 0, stream>>>(
      KSP, VSP, WKS, WVS, wk_b, wv_b, KHT, VHT);
  compute_m_mfma<<<dim3(8, 64), blk, 0, stream>>>(KHT, VHT, M);
  split_m_bias_kernel<<<64, blk, 0, stream>>>(M, wq_b, MSP, BQM);
  wqm_kernel<<<dim3(16, H, B), blk, 0, stream>>>(WQA, MSP, WQM);
  // fused logit GEMM + softmax: 256x128 tiles (full 256-block grid)
  gemm256<2, 1, 3072><<<dim3(8, 32, 1), dim3(512), 0, stream>>>(
      QSP, nullptr, WQM, nullptr, BQM, nullptr, HB, nullptr);
  // output projection: plain bf16, K=1024, 256x128 tiles
  gemm256<2, 0, 1024><<<dim3(8, 32, 1), dim3(512), 0, stream>>>(
      HB, HB, WOB, WOB, wo_b, wo_b, out, out);
}

// Round 6
// 429.470 us; speedup vs baseline: 1.2095x; 1.2095x over previous
//
#include <hip/hip_runtime.h>
#include <math.h>

#define B 4
#define S 2048
#define D 1024
#define H 16
#define DK 64
#define MS (B * S)   // 8192
#define GKA 2048     // split storage width: [hi | lo]

typedef short bf16x8 __attribute__((ext_vector_type(8)));
typedef float f32x4 __attribute__((ext_vector_type(4)));

__device__ __forceinline__ unsigned short f2bf(float x) {
  union { float f; unsigned u; } v; v.f = x;
  unsigned r = v.u + 0x7fff + ((v.u >> 16) & 1);  // RNE
  return (unsigned short)(r >> 16);
}
__device__ __forceinline__ float bf2f(unsigned short h) {
  union { unsigned u; float f; } v; v.u = ((unsigned)h) << 16;
  return v.f;
}
__device__ __forceinline__ void split2(float x, unsigned short& hi, unsigned short& lo) {
  hi = f2bf(x);
  lo = f2bf(x - bf2f(hi));
}

// ---------------------------------------------------------------------------
// prep: ALL input preprocessing in one launch, chunked by blockIdx.x:
//  [0,24576)      split k,v,q -> KSP,VSP,QSP  [8192][2048] ([hi|lo])
//  [24576,32768)  split wk,wv -> WKS,WVS      [1024][2048] (B^T layout)
//  [32768,36864)  split wq    -> WQA [16][1024][128] (A layout, [hi|lo] along k)
//  [36864,37888)  cast wo     -> WOB [1024][1024] plain bf16 (B^T layout)
//  [37888,38144)  zero M
// ---------------------------------------------------------------------------
__global__ __launch_bounds__(256) void prep_kernel(
    const float* __restrict__ q, const float* __restrict__ k, const float* __restrict__ v,
    const float* __restrict__ wk, const float* __restrict__ wv, const float* __restrict__ wq,
    const float* __restrict__ wo,
    unsigned short* __restrict__ KSP, unsigned short* __restrict__ VSP,
    unsigned short* __restrict__ QSP,
    unsigned short* __restrict__ WKS, unsigned short* __restrict__ WVS,
    unsigned short* __restrict__ WQA, unsigned short* __restrict__ WOB,
    float* __restrict__ M) {
  const int blk = blockIdx.x;
  const int tid = threadIdx.x;
  if (blk < 24576) {  // activation splits
    const int which = blk >> 13;
    const int bb = blk & 8191;
    const float* X = which == 0 ? k : (which == 1 ? v : q);
    unsigned short* O = which == 0 ? KSP : (which == 1 ? VSP : QSP);
    int t = bb * 256 + tid;
    int idx = t * 4;
    int m = idx >> 10, d = idx & 1023;
    float4 x = *(const float4*)&X[idx];
    union { unsigned short h[4]; ushort4 u; } uh, ul;
    split2(x.x, uh.h[0], ul.h[0]);
    split2(x.y, uh.h[1], ul.h[1]);
    split2(x.z, uh.h[2], ul.h[2]);
    split2(x.w, uh.h[3], ul.h[3]);
    *(ushort4*)&O[(size_t)m * GKA + d] = uh.u;
    *(ushort4*)&O[(size_t)m * GKA + 1024 + d] = ul.u;
  } else if (blk < 32768) {  // wk/wv splits (B^T layout)
    const int which = (blk - 24576) >> 12;
    const int bb = (blk - 24576) & 4095;
    const float* W = which == 0 ? wk : wv;
    unsigned short* O = which == 0 ? WKS : WVS;
    int t = bb * 256 + tid;
    int d = t & 1023, n = t >> 10;
    int h = n >> 6, dk = n & 63;
    float x = W[((size_t)(h << 10) + d) * 64 + dk];
    unsigned short hi, lo;
    split2(x, hi, lo);
    size_t ro = (size_t)n * GKA + d;
    O[ro] = hi;
    O[ro + 1024] = lo;
  } else if (blk < 36864) {  // wq split (A layout: [h][d][hi 64|lo 64])
    int t = (blk - 32768) * 256 + tid;  // 1M = 16*1024*64
    int kk = t & 63;
    int hd = t >> 6;  // h*1024 + d
    float x = wq[t];
    unsigned short hi, lo;
    split2(x, hi, lo);
    WQA[(size_t)hd * 128 + kk] = hi;
    WQA[(size_t)hd * 128 + 64 + kk] = lo;
  } else if (blk < 37888) {  // wo cast
    int t = (blk - 36864) * 256 + tid;
    int idx = t * 4;
    float4 x = *(const float4*)&wo[idx];
    ushort4 u;
    u.x = f2bf(x.x); u.y = f2bf(x.y); u.z = f2bf(x.z); u.w = f2bf(x.w);
    *(ushort4*)&WOB[idx] = u;
  } else {  // zero M (256 blocks * 256 threads * 4 = 262144 floats)
    int t = (blk - 37888) * 256 + tid;
    *(float4*)&M[(size_t)t * 4] = (float4){0.f, 0.f, 0.f, 0.f};
  }
}

// ---------------------------------------------------------------------------
// gemm256: templated 256xBN-tile 8-wave GEMM core, phase-level A-prefetch,
// + T1 XCD-aware bijective block swizzle (pure index remap, compile-time dims).
// NWC: waves along N (4 -> BN=256, 2 -> BN=128). NWR = 8/NWC waves along M.
// EPI: 0 = fp32 + bias store; 1 = per-head softmax -> bf16.
// KLOG: 3072 (Markidis 3-term split, stride 2048, wrap) or 1024 (plain bf16).
// Core schedule identical to the verified round-4 kernel (112 VGPR, no spill).
// ---------------------------------------------------------------------------
__device__ __forceinline__ void gll(const unsigned short* g, unsigned short* l) {
  __builtin_amdgcn_global_load_lds((const __attribute__((address_space(1))) void*)g,
                                   (__attribute__((address_space(3))) void*)l, 16, 0, 0);
}

template <int NWC>
__device__ __forceinline__ void stageT(
    const unsigned short* __restrict__ A, const unsigned short* __restrict__ BT,
    const unsigned* aoffs, const unsigned* boffs,
    unsigned short* Asb, unsigned short* Bsb, int aof, int bof, int w) {
#pragma unroll
  for (int g = 0; g < 4; ++g) gll(A + aoffs[g] + aof, Asb + g * 4096 + w * 512);
#pragma unroll
  for (int g = 0; g < NWC; ++g) gll(BT + boffs[g] + bof, Bsb + g * 4096 + w * 512);
}

template <int NWC, int EPI, int KLOG>
__global__ __launch_bounds__(512, 2) void gemm256(
    const unsigned short* __restrict__ A0, const unsigned short* __restrict__ A1,
    const unsigned short* __restrict__ Bt0, const unsigned short* __restrict__ Bt1,
    const float* __restrict__ bias0, const float* __restrict__ bias1,
    void* __restrict__ C0, void* __restrict__ C1) {
  constexpr int NWR = 8 / NWC;          // waves along M
  constexpr int MR = (256 / NWR) / 16;  // A-frags per wave (8 or 4)
  constexpr int NPH = MR / 2;           // phases per tile (4 or 2)
  constexpr int BN = NWC * 64;          // tile N
  constexpr int AST = (KLOG == 1024) ? 1024 : 2048;
  constexpr int NKT = KLOG / 64;        // K-tiles
  constexpr int GX = 1024 / BN;         // grid x (4 or 8), power of 2
  constexpr int NWG = GX * 32;          // blocks per z (128 or 256), %8 == 0
  constexpr int CPX = NWG / 8;          // chunk per XCD

  __shared__ __align__(16) unsigned short As[2][256 * 64];
  __shared__ __align__(16) unsigned short Bs[2][BN * 64];

  const int tid = threadIdx.x;
  const int lane = tid & 63;
  const int w = tid >> 6;
  const int wr = w / NWC;
  const int wc = w % NWC;
  const int fm = lane & 15;
  const int quad = lane >> 4;
  const int sx = (fm & 7) << 3;

  // T1: bijective XCD swizzle of the (x,y) block index (NWG % 8 == 0)
  int lin = blockIdx.y * GX + blockIdx.x;
  lin = (lin & 7) * CPX + (lin >> 3);
  const int bxs = lin & (GX - 1);
  const int bys = lin / GX;
  const size_t bm = (size_t)bys * 256;
  const size_t bn = (size_t)bxs * BN;

  const unsigned short* A;
  const unsigned short* BT;
  const float* bias;
  if constexpr (EPI == 1) {
    const int b = bys >> 3;  // 2048 rows per batch / 256-row tiles
    A = A0;
    BT = Bt0 + (size_t)b * D * GKA;
    bias = bias0 + (size_t)b * D;
  } else {
    A = blockIdx.z ? A1 : A0;
    BT = blockIdx.z ? Bt1 : Bt0;
    bias = blockIdx.z ? bias1 : bias0;
  }

  // staging source offsets (col pre-swizzled -> linear LDS dest = swizzled tile)
  const int srow = tid >> 3;                        // 0..63 within 64-row group
  const int scol = ((tid & 7) ^ (srow & 7)) << 3;   // swizzled col (ushorts)
  unsigned aoffs[4], boffs[NWC];
#pragma unroll
  for (int g = 0; g < 4; ++g) aoffs[g] = (unsigned)((bm + g * 64 + srow) * AST + scol);
#pragma unroll
  for (int g = 0; g < NWC; ++g) boffs[g] = (unsigned)((bn + g * 64 + srow) * AST + scol);

  // read-side bases: low-6-bit field (kk*32 + quad*8) ^ sx; rows add >=bit6.
  const int basek0 = (quad * 8) ^ sx;
  const int basek1 = (32 + quad * 8) ^ sx;
  const int arow0 = (wr * (MR * 16) + fm) * 64;
  const int brow0 = (wc * 64 + fm) * 64;

  f32x4 acc[MR][4];
#pragma unroll
  for (int i = 0; i < MR; ++i)
#pragma unroll
    for (int j = 0; j < 4; ++j) acc[i][j] = (f32x4){0.f, 0.f, 0.f, 0.f};

  auto ka = [](int k0) { return (KLOG == 3072) ? (k0 < 2048 ? k0 : k0 - 2048) : k0; };
  auto kb = [](int k0) { return (KLOG == 3072) ? (k0 < 1024 ? k0 : k0 - 1024) : k0; };

  // prologue: tiles 0 and 1 in flight
  stageT<NWC>(A, BT, aoffs, boffs, As[0], Bs[0], ka(0), kb(0), w);
  stageT<NWC>(A, BT, aoffs, boffs, As[1], Bs[1], ka(64), kb(64), w);

#pragma unroll 1
  for (int t = 0; t < NKT; ++t) {
    const unsigned short* Ab = As[t & 1];
    const unsigned short* Bb = Bs[t & 1];
    unsigned short* Asb = As[t & 1];
    unsigned short* Bsb = Bs[t & 1];

    if (t < NKT - 1) {
      if constexpr (NWC == 4) asm volatile("s_waitcnt vmcnt(8)" ::: "memory");
      else                    asm volatile("s_waitcnt vmcnt(6)" ::: "memory");
    } else {
      asm volatile("s_waitcnt vmcnt(0)" ::: "memory");
    }
    __builtin_amdgcn_s_barrier();       // B0: tile t visible to all waves
    __builtin_amdgcn_sched_barrier(0);

    bf16x8 bfr[4][2];
    bf16x8 afr[2][2][2];  // [phase parity][row][kk]

    // initial reads: all B-frags + phase-0 A-frags (12 ds_read_b128)
#pragma unroll
    for (int j = 0; j < 4; ++j) {
      bfr[j][0] = *(const bf16x8*)&Bb[brow0 + j * 1024 + basek0];
      bfr[j][1] = *(const bf16x8*)&Bb[brow0 + j * 1024 + basek1];
    }
#pragma unroll
    for (int ii = 0; ii < 2; ++ii) {
      afr[0][ii][0] = *(const bf16x8*)&Ab[arow0 + ii * 1024 + basek0];
      afr[0][ii][1] = *(const bf16x8*)&Ab[arow0 + ii * 1024 + basek1];
    }
    __builtin_amdgcn_sched_barrier(0);

#pragma unroll
    for (int qq = 0; qq < NPH; ++qq) {
      if (qq + 1 < NPH) {
        // prefetch next phase's A-frags; they drain under this phase's MFMAs
#pragma unroll
        for (int ii = 0; ii < 2; ++ii) {
          afr[(qq + 1) & 1][ii][0] =
              *(const bf16x8*)&Ab[arow0 + ((qq + 1) * 2 + ii) * 1024 + basek0];
          afr[(qq + 1) & 1][ii][1] =
              *(const bf16x8*)&Ab[arow0 + ((qq + 1) * 2 + ii) * 1024 + basek1];
        }
        asm volatile("s_waitcnt lgkmcnt(4)" ::: "memory");  // current phase ready
      } else {
        asm volatile("s_waitcnt lgkmcnt(0)" ::: "memory");  // last phase: drain
      }
      __builtin_amdgcn_sched_barrier(0);  // rule #18: pin MFMA below the wait
      __builtin_amdgcn_s_setprio(1);
#pragma unroll
      for (int ii = 0; ii < 2; ++ii)
#pragma unroll
        for (int j = 0; j < 4; ++j) {
          acc[qq * 2 + ii][j] = __builtin_amdgcn_mfma_f32_16x16x32_bf16(
              afr[qq & 1][ii][0], bfr[j][0], acc[qq * 2 + ii][j], 0, 0, 0);
          acc[qq * 2 + ii][j] = __builtin_amdgcn_mfma_f32_16x16x32_bf16(
              afr[qq & 1][ii][1], bfr[j][1], acc[qq * 2 + ii][j], 0, 0, 0);
        }
      __builtin_amdgcn_s_setprio(0);
      __builtin_amdgcn_sched_barrier(0);
    }

    __builtin_amdgcn_s_barrier();       // B1: all waves done reading buf
    if (t + 2 < NKT) {
      const int k0 = (t + 2) * 64;
      stageT<NWC>(A, BT, aoffs, boffs, Asb, Bsb, ka(k0), kb(k0), w);
    }
  }

  if constexpr (EPI == 0) {
    float* C = (float*)(blockIdx.z ? C1 : C0);
#pragma unroll
    for (int i = 0; i < MR; ++i)
#pragma unroll
      for (int j = 0; j < 4; ++j) {
        size_t row = bm + wr * (MR * 16) + i * 16 + quad * 4;
        size_t col = bn + wc * 64 + j * 16 + fm;
        float bb = bias[col];
#pragma unroll
        for (int r = 0; r < 4; ++r) C[(row + r) * D + col] = acc[i][j][r] + bb;
      }
  } else {
    // softmax over this wave's 64 cols (= one full head), bf16 out
    unsigned short* HB = (unsigned short*)C0;
    const size_t head_col0 = bn + wc * 64;
    float bj[4];
#pragma unroll
    for (int j = 0; j < 4; ++j) bj[j] = bias[head_col0 + j * 16 + fm];
#pragma unroll
    for (int i = 0; i < MR; ++i) {
      f32x4 val[4];
#pragma unroll
      for (int j = 0; j < 4; ++j)
#pragma unroll
        for (int r = 0; r < 4; ++r) val[j][r] = (acc[i][j][r] + bj[j]) * 0.125f;

      f32x4 mx = val[0];
#pragma unroll
      for (int j = 1; j < 4; ++j)
#pragma unroll
        for (int r = 0; r < 4; ++r) mx[r] = fmaxf(mx[r], val[j][r]);
#pragma unroll
      for (int off = 1; off < 16; off <<= 1)
#pragma unroll
        for (int r = 0; r < 4; ++r) mx[r] = fmaxf(mx[r], __shfl_xor(mx[r], off, 64));

      f32x4 e[4];
      f32x4 sm = (f32x4){0.f, 0.f, 0.f, 0.f};
#pragma unroll
      for (int j = 0; j < 4; ++j)
#pragma unroll
        for (int r = 0; r < 4; ++r) {
          e[j][r] = __expf(val[j][r] - mx[r]);
          sm[r] += e[j][r];
        }
#pragma unroll
      for (int off = 1; off < 16; off <<= 1)
#pragma unroll
        for (int r = 0; r < 4; ++r) sm[r] += __shfl_xor(sm[r], off, 64);

      f32x4 inv;
#pragma unroll
      for (int r = 0; r < 4; ++r) inv[r] = 1.0f / sm[r];

#pragma unroll
      for (int j = 0; j < 4; ++j)
#pragma unroll
        for (int r = 0; r < 4; ++r) {
          size_t row = bm + wr * (MR * 16) + i * 16 + quad * 4 + r;
          HB[row * D + head_col0 + j * 16 + fm] = f2bf(e[j][r] * inv[r]);
        }
    }
  }
}

// ---------------------------------------------------------------------------
// M[b,h] = kh^T @ vh (64x64 per (b,h)), s-split 8-way with atomics.
// ---------------------------------------------------------------------------
__global__ __launch_bounds__(256) void compute_m_kernel(
    const float* __restrict__ KH, const float* __restrict__ VH, float* __restrict__ Mout) {
  const int sc = blockIdx.x, h = blockIdx.y, b = blockIdx.z;
  const int tid = threadIdx.x;
  const int i0 = (tid >> 4) * 4;
  const int j0 = (tid & 15) * 4;
  __shared__ float ks[16][64], vs[16][64];
  float acc[4][4];
#pragma unroll
  for (int a = 0; a < 4; a++)
#pragma unroll
    for (int c = 0; c < 4; c++) acc[a][c] = 0.f;

  const int s0 = sc * (S / 8);
  const int rr = tid >> 4;
  const int cc = (tid & 15) * 4;
  for (int s = s0; s < s0 + S / 8; s += 16) {
    size_t base = ((size_t)b * S + s + rr) * D + h * 64 + cc;
    __syncthreads();
    *(float4*)&ks[rr][cc] = *(const float4*)&KH[base];
    *(float4*)&vs[rr][cc] = *(const float4*)&VH[base];
    __syncthreads();
#pragma unroll
    for (int ss = 0; ss < 16; ss++) {
      float4 kf = *(const float4*)&ks[ss][i0];
      float4 vf = *(const float4*)&vs[ss][j0];
      float ka[4] = {kf.x, kf.y, kf.z, kf.w};
      float va[4] = {vf.x, vf.y, vf.z, vf.w};
#pragma unroll
      for (int a = 0; a < 4; a++)
#pragma unroll
        for (int c = 0; c < 4; c++) acc[a][c] += ka[a] * va[c];
    }
  }
  float* Mp = Mout + ((size_t)(b * H + h)) * DK * DK;
#pragma unroll
  for (int a = 0; a < 4; a++)
#pragma unroll
    for (int c = 0; c < 4; c++) atomicAdd(&Mp[(i0 + a) * DK + j0 + c], acc[a][c]);
}

// ---------------------------------------------------------------------------
// split_m_bias: M fp32 [bh][64k][64n] -> MSP bf16 [bh][2][64n][64k] (transposed
// hi,lo) AND BQM[bh][64 j] = sum_k bq[h,k]*M[k,j]  (unscaled).
// ---------------------------------------------------------------------------
__global__ __launch_bounds__(256) void split_m_bias_kernel(
    const float* __restrict__ M, const float* __restrict__ bq,
    unsigned short* __restrict__ MSP, float* __restrict__ BQM) {
  const int bh = blockIdx.x;
  const int h = bh & 15;
  const float* Mp = M + (size_t)bh * 4096;
  unsigned short* hiP = MSP + (size_t)bh * 8192;
  unsigned short* loP = hiP + 4096;
  for (int idx = threadIdx.x; idx < 4096; idx += 256) {
    int kk = idx >> 6, nn = idx & 63;
    unsigned short hi, lo;
    split2(Mp[idx], hi, lo);
    hiP[nn * 64 + kk] = hi;
    loP[nn * 64 + kk] = lo;
  }
  if (threadIdx.x < 64) {
    int j = threadIdx.x;
    float a = 0.f;
#pragma unroll 8
    for (int kk = 0; kk < 64; kk++) a += bq[h * 64 + kk] * Mp[kk * 64 + j];
    BQM[(size_t)bh * 64 + j] = a;
  }
}

// ---------------------------------------------------------------------------
// wqm: Wq'[b,h] = Wq[h] @ M[b,h]  (1024x64 per pair), 3-term split MFMA.
// A = WQA [h][1024 d][hi64|lo64]; B = MSP [bh][2][64 n][64 k] (transposed).
// Output WQM [b][n=h*64+j][d hi | 1024+d lo] (B^T layout for the qsm GEMM).
// grid (16, H, B); block = 64 d-rows; wave w owns d-rows [c*64+w*16, +16).
// ---------------------------------------------------------------------------
__global__ __launch_bounds__(256) void wqm_kernel(
    const unsigned short* __restrict__ WQA, const unsigned short* __restrict__ MSP,
    unsigned short* __restrict__ WQM) {
  const int c = blockIdx.x, h = blockIdx.y, b = blockIdx.z;
  const int tid = threadIdx.x;
  const int lane = tid & 63;
  const int w = tid >> 6;
  const int fm = lane & 15;
  const int quad = lane >> 4;
  const int ko = quad * 8;
  const int dbase = c * 64 + w * 16;

  const unsigned short* arow = WQA + ((size_t)h * 1024 + dbase + fm) * 128;
  bf16x8 ahi0 = *(const bf16x8*)&arow[ko];        // k 0..31 hi
  bf16x8 ahi1 = *(const bf16x8*)&arow[32 + ko];   // k 32..63 hi
  bf16x8 alo0 = *(const bf16x8*)&arow[64 + ko];   // k 0..31 lo
  bf16x8 alo1 = *(const bf16x8*)&arow[96 + ko];   // k 32..63 lo

  const unsigned short* hiP = MSP + ((size_t)(b * H + h)) * 8192;
  const unsigned short* loP = hiP + 4096;
  f32x4 acc[4];
#pragma unroll
  for (int j = 0; j < 4; j++) acc[j] = (f32x4){0.f, 0.f, 0.f, 0.f};
#pragma unroll
  for (int j = 0; j < 4; j++) {
    bf16x8 bhi0 = *(const bf16x8*)&hiP[(j * 16 + fm) * 64 + ko];
    bf16x8 bhi1 = *(const bf16x8*)&hiP[(j * 16 + fm) * 64 + 32 + ko];
    bf16x8 blo0 = *(const bf16x8*)&loP[(j * 16 + fm) * 64 + ko];
    bf16x8 blo1 = *(const bf16x8*)&loP[(j * 16 + fm) * 64 + 32 + ko];
    acc[j] = __builtin_amdgcn_mfma_f32_16x16x32_bf16(ahi0, bhi0, acc[j], 0, 0, 0);
    acc[j] = __builtin_amdgcn_mfma_f32_16x16x32_bf16(ahi1, bhi1, acc[j], 0, 0, 0);
    acc[j] = __builtin_amdgcn_mfma_f32_16x16x32_bf16(alo0, bhi0, acc[j], 0, 0, 0);
    acc[j] = __builtin_amdgcn_mfma_f32_16x16x32_bf16(alo1, bhi1, acc[j], 0, 0, 0);
    acc[j] = __builtin_amdgcn_mfma_f32_16x16x32_bf16(ahi0, blo0, acc[j], 0, 0, 0);
    acc[j] = __builtin_amdgcn_mfma_f32_16x16x32_bf16(ahi1, blo1, acc[j], 0, 0, 0);
  }

  // C[d=dbase+quad*4+r][col j*16+fm]; write split to WQM[b][h*64+col][d]
#pragma unroll
  for (int j = 0; j < 4; j++) {
    int n = h * 64 + j * 16 + fm;
    ushort4 hv, lv;
    unsigned short hi, lo;
    split2(acc[j][0], hi, lo); hv.x = hi; lv.x = lo;
    split2(acc[j][1], hi, lo); hv.y = hi; lv.y = lo;
    split2(acc[j][2], hi, lo); hv.z = hi; lv.z = lo;
    split2(acc[j][3], hi, lo); hv.w = hi; lv.w = lo;
    size_t base = ((size_t)b * D + n) * GKA + dbase + quad * 4;
    *(ushort4*)&WQM[base] = hv;
    *(ushort4*)&WQM[base + 1024] = lv;
  }
}

// ---------------------------------------------------------------------------
extern "C" void kernel_launch(void* const* d_in, const int* in_sizes, int n_in,
                              void* d_out, int out_size, void* d_ws, size_t ws_size,
                              hipStream_t stream) {
  const float* q = (const float*)d_in[0];
  const float* k = (const float*)d_in[1];
  const float* v = (const float*)d_in[2];
  const float* wq_w = (const float*)d_in[3];
  const float* wq_b = (const float*)d_in[4];
  const float* wk_w = (const float*)d_in[5];
  const float* wk_b = (const float*)d_in[6];
  const float* wv_w = (const float*)d_in[7];
  const float* wv_b = (const float*)d_in[8];
  const float* wo_w = (const float*)d_in[9];
  const float* wo_b = (const float*)d_in[10];
  float* out = (float*)d_out;

  // ws (143 MB): KSP 32 (->HB 16 | WQM 16) | VSP 32 (->MSP 1 + BQM) | QSP 32 |
  //              VH 32 | M 1 | WKS 4 | WVS 4 | WQA 4 | WOB 2.   KH lives in d_out.
  unsigned short* KSP = (unsigned short*)d_ws;
  unsigned short* VSP = KSP + (size_t)16 * 1024 * 1024;
  unsigned short* QSP = VSP + (size_t)16 * 1024 * 1024;
  float* VH = (float*)(QSP + (size_t)16 * 1024 * 1024);
  float* M = VH + (size_t)MS * D;
  unsigned short* WKS = (unsigned short*)(M + 256 * 1024);
  unsigned short* WVS = WKS + (size_t)2 * 1024 * 1024;
  unsigned short* WQA = WVS + (size_t)2 * 1024 * 1024;
  unsigned short* WOB = WQA + (size_t)2 * 1024 * 1024;
  // aliases
  float* KH = out;                                   // dead after compute_m
  unsigned short* HB = KSP;                          // KSP dead after gemm KV
  unsigned short* WQM = KSP + (size_t)8 * 1024 * 1024;
  unsigned short* MSP = VSP;                         // VSP dead after gemm KV
  float* BQM = (float*)(VSP + 512 * 1024);

  dim3 blk(256);

  prep_kernel<<<38144, blk, 0, stream>>>(q, k, v, wk_w, wv_w, wq_w, wo_w,
                                         KSP, VSP, QSP, WKS, WVS, WQA, WOB, M);
  // K/V projections: 256x256 tiles, split-Markidis K=3072
  gemm256<4, 0, 3072><<<dim3(4, 32, 2), dim3(512), 0, stream>>>(
      KSP, VSP, WKS, WVS, wk_b, wv_b, KH, VH);
  compute_m_kernel<<<dim3(8, H, B), blk, 0, stream>>>(KH, VH, M);
  split_m_bias_kernel<<<64, blk, 0, stream>>>(M, wq_b, MSP, BQM);
  wqm_kernel<<<dim3(16, H, B), blk, 0, stream>>>(WQA, MSP, WQM);
  // fused logit GEMM + softmax: 256x128 tiles (full 256-block grid)
  gemm256<2, 1, 3072><<<dim3(8, 32, 1), dim3(512), 0, stream>>>(
      QSP, nullptr, WQM, nullptr, BQM, nullptr, HB, nullptr);
  // output projection: plain bf16, K=1024, 256x128 tiles
  gemm256<2, 0, 1024><<<dim3(8, 32, 1), dim3(512), 0, stream>>>(
      HB, HB, WOB, WOB, wo_b, wo_b, out, out);
}

// Round 7
// 415.330 us; speedup vs baseline: 1.2507x; 1.0340x over previous
//
#include <hip/hip_runtime.h>
#include <math.h>

#define B 4
#define S 2048
#define D 1024
#define H 16
#define DK 64
#define MS (B * S)   // 8192
#define GKA 2048     // split storage width: [hi | lo]

typedef short bf16x8 __attribute__((ext_vector_type(8)));
typedef float f32x4 __attribute__((ext_vector_type(4)));

__device__ __forceinline__ unsigned short f2bf(float x) {
  union { float f; unsigned u; } v; v.f = x;
  unsigned r = v.u + 0x7fff + ((v.u >> 16) & 1);  // RNE
  return (unsigned short)(r >> 16);
}
__device__ __forceinline__ float bf2f(unsigned short h) {
  union { unsigned u; float f; } v; v.u = ((unsigned)h) << 16;
  return v.f;
}
__device__ __forceinline__ void split2(float x, unsigned short& hi, unsigned short& lo) {
  hi = f2bf(x);
  lo = f2bf(x - bf2f(hi));
}

// ---------------------------------------------------------------------------
// prep: ALL input preprocessing in one launch, chunked by blockIdx.x:
//  [0,24576)      split k,v,q -> KSP,VSP,QSP  [8192][2048] ([hi|lo])
//  [24576,32768)  split wk,wv -> WKS,WVS      [1024][2048] (B^T layout)
//  [32768,36864)  split wq    -> WQA [16][1024][128] (A layout, [hi|lo] along k)
//  [36864,37888)  cast wo     -> WOB [1024][1024] plain bf16 (B^T layout)
//  [37888,38144)  zero M
// ---------------------------------------------------------------------------
__global__ __launch_bounds__(256) void prep_kernel(
    const float* __restrict__ q, const float* __restrict__ k, const float* __restrict__ v,
    const float* __restrict__ wk, const float* __restrict__ wv, const float* __restrict__ wq,
    const float* __restrict__ wo,
    unsigned short* __restrict__ KSP, unsigned short* __restrict__ VSP,
    unsigned short* __restrict__ QSP,
    unsigned short* __restrict__ WKS, unsigned short* __restrict__ WVS,
    unsigned short* __restrict__ WQA, unsigned short* __restrict__ WOB,
    float* __restrict__ M) {
  const int blk = blockIdx.x;
  const int tid = threadIdx.x;
  if (blk < 24576) {  // activation splits
    const int which = blk >> 13;
    const int bb = blk & 8191;
    const float* X = which == 0 ? k : (which == 1 ? v : q);
    unsigned short* O = which == 0 ? KSP : (which == 1 ? VSP : QSP);
    int t = bb * 256 + tid;
    int idx = t * 4;
    int m = idx >> 10, d = idx & 1023;
    float4 x = *(const float4*)&X[idx];
    union { unsigned short h[4]; ushort4 u; } uh, ul;
    split2(x.x, uh.h[0], ul.h[0]);
    split2(x.y, uh.h[1], ul.h[1]);
    split2(x.z, uh.h[2], ul.h[2]);
    split2(x.w, uh.h[3], ul.h[3]);
    *(ushort4*)&O[(size_t)m * GKA + d] = uh.u;
    *(ushort4*)&O[(size_t)m * GKA + 1024 + d] = ul.u;
  } else if (blk < 32768) {  // wk/wv splits (B^T layout)
    const int which = (blk - 24576) >> 12;
    const int bb = (blk - 24576) & 4095;
    const float* W = which == 0 ? wk : wv;
    unsigned short* O = which == 0 ? WKS : WVS;
    int t = bb * 256 + tid;
    int d = t & 1023, n = t >> 10;
    int h = n >> 6, dk = n & 63;
    float x = W[((size_t)(h << 10) + d) * 64 + dk];
    unsigned short hi, lo;
    split2(x, hi, lo);
    size_t ro = (size_t)n * GKA + d;
    O[ro] = hi;
    O[ro + 1024] = lo;
  } else if (blk < 36864) {  // wq split (A layout: [h][d][hi 64|lo 64])
    int t = (blk - 32768) * 256 + tid;  // 1M = 16*1024*64
    int kk = t & 63;
    int hd = t >> 6;  // h*1024 + d
    float x = wq[t];
    unsigned short hi, lo;
    split2(x, hi, lo);
    WQA[(size_t)hd * 128 + kk] = hi;
    WQA[(size_t)hd * 128 + 64 + kk] = lo;
  } else if (blk < 37888) {  // wo cast
    int t = (blk - 36864) * 256 + tid;
    int idx = t * 4;
    float4 x = *(const float4*)&wo[idx];
    ushort4 u;
    u.x = f2bf(x.x); u.y = f2bf(x.y); u.z = f2bf(x.z); u.w = f2bf(x.w);
    *(ushort4*)&WOB[idx] = u;
  } else {  // zero M (256 blocks * 256 threads * 4 = 262144 floats)
    int t = (blk - 37888) * 256 + tid;
    *(float4*)&M[(size_t)t * 4] = (float4){0.f, 0.f, 0.f, 0.f};
  }
}

// ---------------------------------------------------------------------------
// gemm256: templated 256xBN-tile 8-wave GEMM core, phase-level A-prefetch,
// T1 XCD-aware bijective block swizzle.
// NWC: waves along N (4 -> BN=256, 2 -> BN=128). NWR = 8/NWC waves along M.
// EPI: 0 = fp32 + bias store; 1 = per-head softmax -> bf16.
// MODE: 0 = plain bf16 GEMM, K=1024, BK=64 (verified round-4 path).
//       1 = split-Markidis 3-term: per tile stage a 32-phys-K chunk with hi
//           and lo INTERLEAVED at 16B-slot granularity:
//             LDS row = [hi0 lo0 hi1 lo1 hi2 lo2 hi3 lo3]  (slots of 8 k)
//           and run all 3 terms (ah*bh + al*bh + ah*bl) per staged tile:
//           96 MFMA / 24 ds_reads / 8 gll per tile, 32 tiles (vs 64/24/8 x48).
// Slot swizzle (both modes): LDS[r][s] = tile[r][s ^ (r&7)]; read applies the
// same XOR (8 lanes/16B-slot -> conflict-free, measured 0). Staging achieves
// it with per-lane pre-swizzled SOURCE addresses + linear gll dest.
// Schedule per tile (identical to verified round-4/6 core):
//   vmcnt(LPS|0) ; B0 barrier ; initial 12 ds_reads ;
//   phases { prefetch next A (4 reads) ; lgkm(4|0) ; setprio MFMA } ;
//   B1 barrier ; stage(t+2).
// ---------------------------------------------------------------------------
__device__ __forceinline__ void gll(const unsigned short* g, unsigned short* l) {
  __builtin_amdgcn_global_load_lds((const __attribute__((address_space(1))) void*)g,
                                   (__attribute__((address_space(3))) void*)l, 16, 0, 0);
}

template <int NWC>
__device__ __forceinline__ void stageT(
    const unsigned short* __restrict__ A, const unsigned short* __restrict__ BT,
    const unsigned* aoffs, const unsigned* boffs,
    unsigned short* Asb, unsigned short* Bsb, int k0, int w) {
#pragma unroll
  for (int g = 0; g < 4; ++g) gll(A + aoffs[g] + k0, Asb + g * 4096 + w * 512);
#pragma unroll
  for (int g = 0; g < NWC; ++g) gll(BT + boffs[g] + k0, Bsb + g * 4096 + w * 512);
}

template <int NWC, int EPI, int MODE>
__global__ __launch_bounds__(512, 2) void gemm256(
    const unsigned short* __restrict__ A0, const unsigned short* __restrict__ A1,
    const unsigned short* __restrict__ Bt0, const unsigned short* __restrict__ Bt1,
    const float* __restrict__ bias0, const float* __restrict__ bias1,
    void* __restrict__ C0, void* __restrict__ C1) {
  constexpr int NWR = 8 / NWC;          // waves along M
  constexpr int MR = (256 / NWR) / 16;  // A-frags per wave (8 or 4)
  constexpr int NPH = MR / 2;           // phases per tile (4 or 2)
  constexpr int BN = NWC * 64;          // tile N
  constexpr int AST = MODE ? 2048 : 1024;  // physical row stride
  constexpr int NKT = MODE ? 32 : 16;   // K-tiles (32x32phys | 16x64)
  constexpr int KSTEP = MODE ? 32 : 64; // physical K per tile
  constexpr int GX = 1024 / BN;         // grid x (4 or 8), power of 2
  constexpr int NWG = GX * 32;          // blocks per z, %8 == 0
  constexpr int CPX = NWG / 8;          // chunk per XCD

  __shared__ __align__(16) unsigned short As[2][256 * 64];
  __shared__ __align__(16) unsigned short Bs[2][BN * 64];

  const int tid = threadIdx.x;
  const int lane = tid & 63;
  const int w = tid >> 6;
  const int wr = w / NWC;
  const int wc = w % NWC;
  const int fm = lane & 15;
  const int quad = lane >> 4;
  const int f7 = fm & 7;

  // T1: bijective XCD swizzle of the (x,y) block index (NWG % 8 == 0)
  int lin = blockIdx.y * GX + blockIdx.x;
  lin = (lin & 7) * CPX + (lin >> 3);
  const int bxs = lin & (GX - 1);
  const int bys = lin / GX;
  const size_t bm = (size_t)bys * 256;
  const size_t bn = (size_t)bxs * BN;

  const unsigned short* A;
  const unsigned short* BT;
  const float* bias;
  if constexpr (EPI == 1) {
    const int b = bys >> 3;  // 2048 rows per batch / 256-row tiles
    A = A0;
    BT = Bt0 + (size_t)b * D * GKA;
    bias = bias0 + (size_t)b * D;
  } else {
    A = blockIdx.z ? A1 : A0;
    BT = blockIdx.z ? Bt1 : Bt0;
    bias = blockIdx.z ? bias1 : bias0;
  }

  // staging source offsets (pre-swizzled source -> linear gll dest = swizzled LDS)
  const int srow = tid >> 3;            // dest row within 64-row group
  int colb;
  if constexpr (MODE) {
    const int tq = (tid & 7) ^ (srow & 7);              // logical slot
    colb = (tq >> 1) * 8 + (tq & 1) * 1024;             // hi at +0, lo at +1024
  } else {
    colb = ((tid & 7) ^ (srow & 7)) << 3;               // plain swizzled col
  }
  unsigned aoffs[4], boffs[NWC];
#pragma unroll
  for (int g = 0; g < 4; ++g) aoffs[g] = (unsigned)((bm + g * 64 + srow) * AST + colb);
#pragma unroll
  for (int g = 0; g < NWC; ++g) boffs[g] = (unsigned)((bn + g * 64 + srow) * AST + colb);

  // read-side frag offsets
  const int arow0 = (wr * (MR * 16) + fm) * 64;
  const int brow0 = (wc * 64 + fm) * 64;
  const int khi = ((quad * 2) ^ f7) * 8;       // MODE1: hi slot
  const int klo = ((quad * 2 + 1) ^ f7) * 8;   // MODE1: lo slot
  const int basek0 = (quad * 8) ^ (f7 << 3);   // MODE0: k-half 0
  const int basek1 = (32 + quad * 8) ^ (f7 << 3);  // MODE0: k-half 1

  f32x4 acc[MR][4];
#pragma unroll
  for (int i = 0; i < MR; ++i)
#pragma unroll
    for (int j = 0; j < 4; ++j) acc[i][j] = (f32x4){0.f, 0.f, 0.f, 0.f};

  // prologue: tiles 0 and 1 in flight
  stageT<NWC>(A, BT, aoffs, boffs, As[0], Bs[0], 0, w);
  stageT<NWC>(A, BT, aoffs, boffs, As[1], Bs[1], KSTEP, w);

#pragma unroll 1
  for (int t = 0; t < NKT; ++t) {
    const unsigned short* Ab = As[t & 1];
    const unsigned short* Bb = Bs[t & 1];
    unsigned short* Asb = As[t & 1];
    unsigned short* Bsb = Bs[t & 1];

    if (t < NKT - 1) {
      if constexpr (NWC == 4) asm volatile("s_waitcnt vmcnt(8)" ::: "memory");
      else                    asm volatile("s_waitcnt vmcnt(6)" ::: "memory");
    } else {
      asm volatile("s_waitcnt vmcnt(0)" ::: "memory");
    }
    __builtin_amdgcn_s_barrier();       // B0: tile t visible to all waves
    __builtin_amdgcn_sched_barrier(0);

    if constexpr (MODE) {
      // ---- split-Markidis 3-term tile: 24 reads, 96 MFMA ----
      bf16x8 bh[4], bl[4];
      bf16x8 ah[2][2], al[2][2];  // [phase parity][row]
#pragma unroll
      for (int j = 0; j < 4; ++j) {
        bh[j] = *(const bf16x8*)&Bb[brow0 + j * 1024 + khi];
        bl[j] = *(const bf16x8*)&Bb[brow0 + j * 1024 + klo];
      }
#pragma unroll
      for (int ii = 0; ii < 2; ++ii) {
        ah[0][ii] = *(const bf16x8*)&Ab[arow0 + ii * 1024 + khi];
        al[0][ii] = *(const bf16x8*)&Ab[arow0 + ii * 1024 + klo];
      }
      __builtin_amdgcn_sched_barrier(0);

#pragma unroll
      for (int qq = 0; qq < NPH; ++qq) {
        if (qq + 1 < NPH) {
#pragma unroll
          for (int ii = 0; ii < 2; ++ii) {
            ah[(qq + 1) & 1][ii] =
                *(const bf16x8*)&Ab[arow0 + ((qq + 1) * 2 + ii) * 1024 + khi];
            al[(qq + 1) & 1][ii] =
                *(const bf16x8*)&Ab[arow0 + ((qq + 1) * 2 + ii) * 1024 + klo];
          }
          asm volatile("s_waitcnt lgkmcnt(4)" ::: "memory");
        } else {
          asm volatile("s_waitcnt lgkmcnt(0)" ::: "memory");
        }
        __builtin_amdgcn_sched_barrier(0);
        __builtin_amdgcn_s_setprio(1);
#pragma unroll
        for (int ii = 0; ii < 2; ++ii)
#pragma unroll
          for (int j = 0; j < 4; ++j) {
            acc[qq * 2 + ii][j] = __builtin_amdgcn_mfma_f32_16x16x32_bf16(
                ah[qq & 1][ii], bh[j], acc[qq * 2 + ii][j], 0, 0, 0);
            acc[qq * 2 + ii][j] = __builtin_amdgcn_mfma_f32_16x16x32_bf16(
                al[qq & 1][ii], bh[j], acc[qq * 2 + ii][j], 0, 0, 0);
            acc[qq * 2 + ii][j] = __builtin_amdgcn_mfma_f32_16x16x32_bf16(
                ah[qq & 1][ii], bl[j], acc[qq * 2 + ii][j], 0, 0, 0);
          }
        __builtin_amdgcn_s_setprio(0);
        __builtin_amdgcn_sched_barrier(0);
      }
    } else {
      // ---- plain bf16 tile (verified round-4 path): 24 reads, 64 MFMA ----
      bf16x8 bfr[4][2];
      bf16x8 afr[2][2][2];  // [phase parity][row][kk]
#pragma unroll
      for (int j = 0; j < 4; ++j) {
        bfr[j][0] = *(const bf16x8*)&Bb[brow0 + j * 1024 + basek0];
        bfr[j][1] = *(const bf16x8*)&Bb[brow0 + j * 1024 + basek1];
      }
#pragma unroll
      for (int ii = 0; ii < 2; ++ii) {
        afr[0][ii][0] = *(const bf16x8*)&Ab[arow0 + ii * 1024 + basek0];
        afr[0][ii][1] = *(const bf16x8*)&Ab[arow0 + ii * 1024 + basek1];
      }
      __builtin_amdgcn_sched_barrier(0);

#pragma unroll
      for (int qq = 0; qq < NPH; ++qq) {
        if (qq + 1 < NPH) {
#pragma unroll
          for (int ii = 0; ii < 2; ++ii) {
            afr[(qq + 1) & 1][ii][0] =
                *(const bf16x8*)&Ab[arow0 + ((qq + 1) * 2 + ii) * 1024 + basek0];
            afr[(qq + 1) & 1][ii][1] =
                *(const bf16x8*)&Ab[arow0 + ((qq + 1) * 2 + ii) * 1024 + basek1];
          }
          asm volatile("s_waitcnt lgkmcnt(4)" ::: "memory");
        } else {
          asm volatile("s_waitcnt lgkmcnt(0)" ::: "memory");
        }
        __builtin_amdgcn_sched_barrier(0);
        __builtin_amdgcn_s_setprio(1);
#pragma unroll
        for (int ii = 0; ii < 2; ++ii)
#pragma unroll
          for (int j = 0; j < 4; ++j) {
            acc[qq * 2 + ii][j] = __builtin_amdgcn_mfma_f32_16x16x32_bf16(
                afr[qq & 1][ii][0], bfr[j][0], acc[qq * 2 + ii][j], 0, 0, 0);
            acc[qq * 2 + ii][j] = __builtin_amdgcn_mfma_f32_16x16x32_bf16(
                afr[qq & 1][ii][1], bfr[j][1], acc[qq * 2 + ii][j], 0, 0, 0);
          }
        __builtin_amdgcn_s_setprio(0);
        __builtin_amdgcn_sched_barrier(0);
      }
    }

    __builtin_amdgcn_s_barrier();       // B1: all waves done reading buf
    if (t + 2 < NKT) {
      stageT<NWC>(A, BT, aoffs, boffs, Asb, Bsb, (t + 2) * KSTEP, w);
    }
  }

  if constexpr (EPI == 0) {
    float* C = (float*)(blockIdx.z ? C1 : C0);
#pragma unroll
    for (int i = 0; i < MR; ++i)
#pragma unroll
      for (int j = 0; j < 4; ++j) {
        size_t row = bm + wr * (MR * 16) + i * 16 + quad * 4;
        size_t col = bn + wc * 64 + j * 16 + fm;
        float bb = bias[col];
#pragma unroll
        for (int r = 0; r < 4; ++r) C[(row + r) * D + col] = acc[i][j][r] + bb;
      }
  } else {
    // softmax over this wave's 64 cols (= one full head), bf16 out
    unsigned short* HB = (unsigned short*)C0;
    const size_t head_col0 = bn + wc * 64;
    float bj[4];
#pragma unroll
    for (int j = 0; j < 4; ++j) bj[j] = bias[head_col0 + j * 16 + fm];
#pragma unroll
    for (int i = 0; i < MR; ++i) {
      f32x4 val[4];
#pragma unroll
      for (int j = 0; j < 4; ++j)
#pragma unroll
        for (int r = 0; r < 4; ++r) val[j][r] = (acc[i][j][r] + bj[j]) * 0.125f;

      f32x4 mx = val[0];
#pragma unroll
      for (int j = 1; j < 4; ++j)
#pragma unroll
        for (int r = 0; r < 4; ++r) mx[r] = fmaxf(mx[r], val[j][r]);
#pragma unroll
      for (int off = 1; off < 16; off <<= 1)
#pragma unroll
        for (int r = 0; r < 4; ++r) mx[r] = fmaxf(mx[r], __shfl_xor(mx[r], off, 64));

      f32x4 e[4];
      f32x4 sm = (f32x4){0.f, 0.f, 0.f, 0.f};
#pragma unroll
      for (int j = 0; j < 4; ++j)
#pragma unroll
        for (int r = 0; r < 4; ++r) {
          e[j][r] = __expf(val[j][r] - mx[r]);
          sm[r] += e[j][r];
        }
#pragma unroll
      for (int off = 1; off < 16; off <<= 1)
#pragma unroll
        for (int r = 0; r < 4; ++r) sm[r] += __shfl_xor(sm[r], off, 64);

      f32x4 inv;
#pragma unroll
      for (int r = 0; r < 4; ++r) inv[r] = 1.0f / sm[r];

#pragma unroll
      for (int j = 0; j < 4; ++j)
#pragma unroll
        for (int r = 0; r < 4; ++r) {
          size_t row = bm + wr * (MR * 16) + i * 16 + quad * 4 + r;
          HB[row * D + head_col0 + j * 16 + fm] = f2bf(e[j][r] * inv[r]);
        }
    }
  }
}

// ---------------------------------------------------------------------------
// M[b,h] = kh^T @ vh (64x64 per (b,h)), s-split 8-way with atomics.
// ---------------------------------------------------------------------------
__global__ __launch_bounds__(256) void compute_m_kernel(
    const float* __restrict__ KH, const float* __restrict__ VH, float* __restrict__ Mout) {
  const int sc = blockIdx.x, h = blockIdx.y, b = blockIdx.z;
  const int tid = threadIdx.x;
  const int i0 = (tid >> 4) * 4;
  const int j0 = (tid & 15) * 4;
  __shared__ float ks[16][64], vs[16][64];
  float acc[4][4];
#pragma unroll
  for (int a = 0; a < 4; a++)
#pragma unroll
    for (int c = 0; c < 4; c++) acc[a][c] = 0.f;

  const int s0 = sc * (S / 8);
  const int rr = tid >> 4;
  const int cc = (tid & 15) * 4;
  for (int s = s0; s < s0 + S / 8; s += 16) {
    size_t base = ((size_t)b * S + s + rr) * D + h * 64 + cc;
    __syncthreads();
    *(float4*)&ks[rr][cc] = *(const float4*)&KH[base];
    *(float4*)&vs[rr][cc] = *(const float4*)&VH[base];
    __syncthreads();
#pragma unroll
    for (int ss = 0; ss < 16; ss++) {
      float4 kf = *(const float4*)&ks[ss][i0];
      float4 vf = *(const float4*)&vs[ss][j0];
      float ka[4] = {kf.x, kf.y, kf.z, kf.w};
      float va[4] = {vf.x, vf.y, vf.z, vf.w};
#pragma unroll
      for (int a = 0; a < 4; a++)
#pragma unroll
        for (int c = 0; c < 4; c++) acc[a][c] += ka[a] * va[c];
    }
  }
  float* Mp = Mout + ((size_t)(b * H + h)) * DK * DK;
#pragma unroll
  for (int a = 0; a < 4; a++)
#pragma unroll
    for (int c = 0; c < 4; c++) atomicAdd(&Mp[(i0 + a) * DK + j0 + c], acc[a][c]);
}

// ---------------------------------------------------------------------------
// split_m_bias: M fp32 [bh][64k][64n] -> MSP bf16 [bh][2][64n][64k] (transposed
// hi,lo) AND BQM[bh][64 j] = sum_k bq[h,k]*M[k,j]  (unscaled).
// ---------------------------------------------------------------------------
__global__ __launch_bounds__(256) void split_m_bias_kernel(
    const float* __restrict__ M, const float* __restrict__ bq,
    unsigned short* __restrict__ MSP, float* __restrict__ BQM) {
  const int bh = blockIdx.x;
  const int h = bh & 15;
  const float* Mp = M + (size_t)bh * 4096;
  unsigned short* hiP = MSP + (size_t)bh * 8192;
  unsigned short* loP = hiP + 4096;
  for (int idx = threadIdx.x; idx < 4096; idx += 256) {
    int kk = idx >> 6, nn = idx & 63;
    unsigned short hi, lo;
    split2(Mp[idx], hi, lo);
    hiP[nn * 64 + kk] = hi;
    loP[nn * 64 + kk] = lo;
  }
  if (threadIdx.x < 64) {
    int j = threadIdx.x;
    float a = 0.f;
#pragma unroll 8
    for (int kk = 0; kk < 64; kk++) a += bq[h * 64 + kk] * Mp[kk * 64 + j];
    BQM[(size_t)bh * 64 + j] = a;
  }
}

// ---------------------------------------------------------------------------
// wqm: Wq'[b,h] = Wq[h] @ M[b,h]  (1024x64 per pair), 3-term split MFMA.
// A = WQA [h][1024 d][hi64|lo64]; B = MSP [bh][2][64 n][64 k] (transposed).
// Output WQM [b][n=h*64+j][d hi | 1024+d lo] (B^T layout for the qsm GEMM).
// grid (16, H, B); block = 64 d-rows; wave w owns d-rows [c*64+w*16, +16).
// ---------------------------------------------------------------------------
__global__ __launch_bounds__(256) void wqm_kernel(
    const unsigned short* __restrict__ WQA, const unsigned short* __restrict__ MSP,
    unsigned short* __restrict__ WQM) {
  const int c = blockIdx.x, h = blockIdx.y, b = blockIdx.z;
  const int tid = threadIdx.x;
  const int lane = tid & 63;
  const int w = tid >> 6;
  const int fm = lane & 15;
  const int quad = lane >> 4;
  const int ko = quad * 8;
  const int dbase = c * 64 + w * 16;

  const unsigned short* arow = WQA + ((size_t)h * 1024 + dbase + fm) * 128;
  bf16x8 ahi0 = *(const bf16x8*)&arow[ko];        // k 0..31 hi
  bf16x8 ahi1 = *(const bf16x8*)&arow[32 + ko];   // k 32..63 hi
  bf16x8 alo0 = *(const bf16x8*)&arow[64 + ko];   // k 0..31 lo
  bf16x8 alo1 = *(const bf16x8*)&arow[96 + ko];   // k 32..63 lo

  const unsigned short* hiP = MSP + ((size_t)(b * H + h)) * 8192;
  const unsigned short* loP = hiP + 4096;
  f32x4 acc[4];
#pragma unroll
  for (int j = 0; j < 4; j++) acc[j] = (f32x4){0.f, 0.f, 0.f, 0.f};
#pragma unroll
  for (int j = 0; j < 4; j++) {
    bf16x8 bhi0 = *(const bf16x8*)&hiP[(j * 16 + fm) * 64 + ko];
    bf16x8 bhi1 = *(const bf16x8*)&hiP[(j * 16 + fm) * 64 + 32 + ko];
    bf16x8 blo0 = *(const bf16x8*)&loP[(j * 16 + fm) * 64 + ko];
    bf16x8 blo1 = *(const bf16x8*)&loP[(j * 16 + fm) * 64 + 32 + ko];
    acc[j] = __builtin_amdgcn_mfma_f32_16x16x32_bf16(ahi0, bhi0, acc[j], 0, 0, 0);
    acc[j] = __builtin_amdgcn_mfma_f32_16x16x32_bf16(ahi1, bhi1, acc[j], 0, 0, 0);
    acc[j] = __builtin_amdgcn_mfma_f32_16x16x32_bf16(alo0, bhi0, acc[j], 0, 0, 0);
    acc[j] = __builtin_amdgcn_mfma_f32_16x16x32_bf16(alo1, bhi1, acc[j], 0, 0, 0);
    acc[j] = __builtin_amdgcn_mfma_f32_16x16x32_bf16(ahi0, blo0, acc[j], 0, 0, 0);
    acc[j] = __builtin_amdgcn_mfma_f32_16x16x32_bf16(ahi1, blo1, acc[j], 0, 0, 0);
  }

  // C[d=dbase+quad*4+r][col j*16+fm]; write split to WQM[b][h*64+col][d]
#pragma unroll
  for (int j = 0; j < 4; j++) {
    int n = h * 64 + j * 16 + fm;
    ushort4 hv, lv;
    unsigned short hi, lo;
    split2(acc[j][0], hi, lo); hv.x = hi; lv.x = lo;
    split2(acc[j][1], hi, lo); hv.y = hi; lv.y = lo;
    split2(acc[j][2], hi, lo); hv.z = hi; lv.z = lo;
    split2(acc[j][3], hi, lo); hv.w = hi; lv.w = lo;
    size_t base = ((size_t)b * D + n) * GKA + dbase + quad * 4;
    *(ushort4*)&WQM[base] = hv;
    *(ushort4*)&WQM[base + 1024] = lv;
  }
}

// ---------------------------------------------------------------------------
extern "C" void kernel_launch(void* const* d_in, const int* in_sizes, int n_in,
                              void* d_out, int out_size, void* d_ws, size_t ws_size,
                              hipStream_t stream) {
  const float* q = (const float*)d_in[0];
  const float* k = (const float*)d_in[1];
  const float* v = (const float*)d_in[2];
  const float* wq_w = (const float*)d_in[3];
  const float* wq_b = (const float*)d_in[4];
  const float* wk_w = (const float*)d_in[5];
  const float* wk_b = (const float*)d_in[6];
  const float* wv_w = (const float*)d_in[7];
  const float* wv_b = (const float*)d_in[8];
  const float* wo_w = (const float*)d_in[9];
  const float* wo_b = (const float*)d_in[10];
  float* out = (float*)d_out;

  // ws (143 MB): KSP 32 (->HB 16 | WQM 16) | VSP 32 (->MSP 1 + BQM) | QSP 32 |
  //              VH 32 | M 1 | WKS 4 | WVS 4 | WQA 4 | WOB 2.   KH lives in d_out.
  unsigned short* KSP = (unsigned short*)d_ws;
  unsigned short* VSP = KSP + (size_t)16 * 1024 * 1024;
  unsigned short* QSP = VSP + (size_t)16 * 1024 * 1024;
  float* VH = (float*)(QSP + (size_t)16 * 1024 * 1024);
  float* M = VH + (size_t)MS * D;
  unsigned short* WKS = (unsigned short*)(M + 256 * 1024);
  unsigned short* WVS = WKS + (size_t)2 * 1024 * 1024;
  unsigned short* WQA = WVS + (size_t)2 * 1024 * 1024;
  unsigned short* WOB = WQA + (size_t)2 * 1024 * 1024;
  // aliases
  float* KH = out;                                   // dead after compute_m
  unsigned short* HB = KSP;                          // KSP dead after gemm KV
  unsigned short* WQM = KSP + (size_t)8 * 1024 * 1024;
  unsigned short* MSP = VSP;                         // VSP dead after gemm KV
  float* BQM = (float*)(VSP + 512 * 1024);

  dim3 blk(256);

  prep_kernel<<<38144, blk, 0, stream>>>(q, k, v, wk_w, wv_w, wq_w, wo_w,
                                         KSP, VSP, QSP, WKS, WVS, WQA, WOB, M);
  // K/V projections: 256x256 tiles, split-Markidis 3-term (MODE 1)
  gemm256<4, 0, 1><<<dim3(4, 32, 2), dim3(512), 0, stream>>>(
      KSP, VSP, WKS, WVS, wk_b, wv_b, KH, VH);
  compute_m_kernel<<<dim3(8, H, B), blk, 0, stream>>>(KH, VH, M);
  split_m_bias_kernel<<<64, blk, 0, stream>>>(M, wq_b, MSP, BQM);
  wqm_kernel<<<dim3(16, H, B), blk, 0, stream>>>(WQA, MSP, WQM);
  // fused logit GEMM + softmax: 256x128 tiles, split 3-term (MODE 1)
  gemm256<2, 1, 1><<<dim3(8, 32, 1), dim3(512), 0, stream>>>(
      QSP, nullptr, WQM, nullptr, BQM, nullptr, HB, nullptr);
  // output projection: plain bf16, K=1024 (MODE 0, verified path)
  gemm256<2, 0, 0><<<dim3(8, 32, 1), dim3(512), 0, stream>>>(
      HB, HB, WOB, WOB, wo_b, wo_b, out, out);
}

// Round 8
// 405.379 us; speedup vs baseline: 1.2814x; 1.0245x over previous
//
#include <hip/hip_runtime.h>
#include <math.h>

#define B 4
#define S 2048
#define D 1024
#define H 16
#define DK 64
#define MS (B * S)   // 8192
#define GKA 2048     // split storage width: [hi | lo]

typedef short bf16x8 __attribute__((ext_vector_type(8)));
typedef float f32x4 __attribute__((ext_vector_type(4)));

__device__ __forceinline__ unsigned short f2bf(float x) {
  union { float f; unsigned u; } v; v.f = x;
  unsigned r = v.u + 0x7fff + ((v.u >> 16) & 1);  // RNE
  return (unsigned short)(r >> 16);
}
__device__ __forceinline__ float bf2f(unsigned short h) {
  union { unsigned u; float f; } v; v.u = ((unsigned)h) << 16;
  return v.f;
}
__device__ __forceinline__ void split2(float x, unsigned short& hi, unsigned short& lo) {
  hi = f2bf(x);
  lo = f2bf(x - bf2f(hi));
}

// ---------------------------------------------------------------------------
// prep: ALL input preprocessing in one launch, chunked by blockIdx.x:
//  [0,24576)      split k,v,q -> KSP,VSP,QSP  [8192][2048] ([hi|lo])
//  [24576,32768)  split wk,wv -> WKS,WVS      [1024][2048] (B^T layout)
//  [32768,36864)  split wq    -> WQA [16][1024][128] (A layout, [hi|lo] along k)
//  [36864,37888)  cast wo     -> WOB [1024][1024] plain bf16 (B^T layout)
//  [37888,38144)  zero M
// ---------------------------------------------------------------------------
__global__ __launch_bounds__(256) void prep_kernel(
    const float* __restrict__ q, const float* __restrict__ k, const float* __restrict__ v,
    const float* __restrict__ wk, const float* __restrict__ wv, const float* __restrict__ wq,
    const float* __restrict__ wo,
    unsigned short* __restrict__ KSP, unsigned short* __restrict__ VSP,
    unsigned short* __restrict__ QSP,
    unsigned short* __restrict__ WKS, unsigned short* __restrict__ WVS,
    unsigned short* __restrict__ WQA, unsigned short* __restrict__ WOB,
    float* __restrict__ M) {
  const int blk = blockIdx.x;
  const int tid = threadIdx.x;
  if (blk < 24576) {  // activation splits
    const int which = blk >> 13;
    const int bb = blk & 8191;
    const float* X = which == 0 ? k : (which == 1 ? v : q);
    unsigned short* O = which == 0 ? KSP : (which == 1 ? VSP : QSP);
    int t = bb * 256 + tid;
    int idx = t * 4;
    int m = idx >> 10, d = idx & 1023;
    float4 x = *(const float4*)&X[idx];
    union { unsigned short h[4]; ushort4 u; } uh, ul;
    split2(x.x, uh.h[0], ul.h[0]);
    split2(x.y, uh.h[1], ul.h[1]);
    split2(x.z, uh.h[2], ul.h[2]);
    split2(x.w, uh.h[3], ul.h[3]);
    *(ushort4*)&O[(size_t)m * GKA + d] = uh.u;
    *(ushort4*)&O[(size_t)m * GKA + 1024 + d] = ul.u;
  } else if (blk < 32768) {  // wk/wv splits (B^T layout)
    const int which = (blk - 24576) >> 12;
    const int bb = (blk - 24576) & 4095;
    const float* W = which == 0 ? wk : wv;
    unsigned short* O = which == 0 ? WKS : WVS;
    int t = bb * 256 + tid;
    int d = t & 1023, n = t >> 10;
    int h = n >> 6, dk = n & 63;
    float x = W[((size_t)(h << 10) + d) * 64 + dk];
    unsigned short hi, lo;
    split2(x, hi, lo);
    size_t ro = (size_t)n * GKA + d;
    O[ro] = hi;
    O[ro + 1024] = lo;
  } else if (blk < 36864) {  // wq split (A layout: [h][d][hi 64|lo 64])
    int t = (blk - 32768) * 256 + tid;  // 1M = 16*1024*64
    int kk = t & 63;
    int hd = t >> 6;  // h*1024 + d
    float x = wq[t];
    unsigned short hi, lo;
    split2(x, hi, lo);
    WQA[(size_t)hd * 128 + kk] = hi;
    WQA[(size_t)hd * 128 + 64 + kk] = lo;
  } else if (blk < 37888) {  // wo cast
    int t = (blk - 36864) * 256 + tid;
    int idx = t * 4;
    float4 x = *(const float4*)&wo[idx];
    ushort4 u;
    u.x = f2bf(x.x); u.y = f2bf(x.y); u.z = f2bf(x.z); u.w = f2bf(x.w);
    *(ushort4*)&WOB[idx] = u;
  } else {  // zero M (256 blocks * 256 threads * 4 = 262144 floats)
    int t = (blk - 37888) * 256 + tid;
    *(float4*)&M[(size_t)t * 4] = (float4){0.f, 0.f, 0.f, 0.f};
  }
}

// ---------------------------------------------------------------------------
// gemm256: templated 256xBN-tile 8-wave GEMM core, phase-level A-prefetch,
// T1 XCD-aware bijective block swizzle.
// NWC: waves along N (4 -> BN=256, 2 -> BN=128). NWR = 8/NWC waves along M.
// EPI: 0 = fp32 + bias store; 1 = per-head softmax -> bf16.
// MODE: 0 = plain bf16 GEMM, K=1024, BK=64 (verified round-4 path).
//       1 = split-Markidis 3-term: per tile stage a 32-phys-K chunk as
//             LDS row = [hi0 hi1 hi2 hi3 | lo0 lo1 lo2 lo3]  (slots of 8 k)
//           (hi chunks in slots 0-3, lo in 4-7) and run all 3 terms
//           (ah*bh + al*bh + ah*bl) per staged tile: 96 MFMA / 24 ds_reads /
//           8 gll per tile, 32 tiles. Read offsets are then byte-identical
//           to MODE0's basek0/basek1 (hi: slot quad^f7, lo: (4+quad)^f7) —
//           the measured-conflict-free pattern (round-7's bit0-adjacent
//           hi/lo pairing caused exactly 4 conflict-cycles/read; bit2
//           separation of paired reads matches MODE0's 0-conflict behavior).
// Slot swizzle (both modes): LDS[r][s] = tile[r][s ^ (r&7)]; staging achieves
// it with per-lane pre-swizzled SOURCE addresses + linear gll dest.
// Schedule per tile (identical to verified round-4/6/7 core):
//   vmcnt(LPS|0) ; B0 barrier ; initial 12 ds_reads ;
//   phases { prefetch next A (4 reads) ; lgkm(4|0) ; setprio MFMA } ;
//   B1 barrier ; stage(t+2).
// ---------------------------------------------------------------------------
__device__ __forceinline__ void gll(const unsigned short* g, unsigned short* l) {
  __builtin_amdgcn_global_load_lds((const __attribute__((address_space(1))) void*)g,
                                   (__attribute__((address_space(3))) void*)l, 16, 0, 0);
}

template <int NWC>
__device__ __forceinline__ void stageT(
    const unsigned short* __restrict__ A, const unsigned short* __restrict__ BT,
    const unsigned* aoffs, const unsigned* boffs,
    unsigned short* Asb, unsigned short* Bsb, int k0, int w) {
#pragma unroll
  for (int g = 0; g < 4; ++g) gll(A + aoffs[g] + k0, Asb + g * 4096 + w * 512);
#pragma unroll
  for (int g = 0; g < NWC; ++g) gll(BT + boffs[g] + k0, Bsb + g * 4096 + w * 512);
}

template <int NWC, int EPI, int MODE>
__global__ __launch_bounds__(512, 2) void gemm256(
    const unsigned short* __restrict__ A0, const unsigned short* __restrict__ A1,
    const unsigned short* __restrict__ Bt0, const unsigned short* __restrict__ Bt1,
    const float* __restrict__ bias0, const float* __restrict__ bias1,
    void* __restrict__ C0, void* __restrict__ C1) {
  constexpr int NWR = 8 / NWC;          // waves along M
  constexpr int MR = (256 / NWR) / 16;  // A-frags per wave (8 or 4)
  constexpr int NPH = MR / 2;           // phases per tile (4 or 2)
  constexpr int BN = NWC * 64;          // tile N
  constexpr int AST = MODE ? 2048 : 1024;  // physical row stride
  constexpr int NKT = MODE ? 32 : 16;   // K-tiles (32x32phys | 16x64)
  constexpr int KSTEP = MODE ? 32 : 64; // physical K per tile
  constexpr int GX = 1024 / BN;         // grid x (4 or 8), power of 2
  constexpr int NWG = GX * 32;          // blocks per z, %8 == 0
  constexpr int CPX = NWG / 8;          // chunk per XCD

  __shared__ __align__(16) unsigned short As[2][256 * 64];
  __shared__ __align__(16) unsigned short Bs[2][BN * 64];

  const int tid = threadIdx.x;
  const int lane = tid & 63;
  const int w = tid >> 6;
  const int wr = w / NWC;
  const int wc = w % NWC;
  const int fm = lane & 15;
  const int quad = lane >> 4;
  const int f7 = fm & 7;

  // T1: bijective XCD swizzle of the (x,y) block index (NWG % 8 == 0)
  int lin = blockIdx.y * GX + blockIdx.x;
  lin = (lin & 7) * CPX + (lin >> 3);
  const int bxs = lin & (GX - 1);
  const int bys = lin / GX;
  const size_t bm = (size_t)bys * 256;
  const size_t bn = (size_t)bxs * BN;

  const unsigned short* A;
  const unsigned short* BT;
  const float* bias;
  if constexpr (EPI == 1) {
    const int b = bys >> 3;  // 2048 rows per batch / 256-row tiles
    A = A0;
    BT = Bt0 + (size_t)b * D * GKA;
    bias = bias0 + (size_t)b * D;
  } else {
    A = blockIdx.z ? A1 : A0;
    BT = blockIdx.z ? Bt1 : Bt0;
    bias = blockIdx.z ? bias1 : bias0;
  }

  // staging source offsets (pre-swizzled source -> linear gll dest = swizzled LDS)
  const int srow = tid >> 3;            // dest row within 64-row group
  int colb;
  if constexpr (MODE) {
    const int tq = (tid & 7) ^ (srow & 7);     // logical slot 0..7
    colb = ((tq & 3) << 3) + (tq >> 2) * 1024; // slots 0-3: hi chunks, 4-7: lo
  } else {
    colb = ((tid & 7) ^ (srow & 7)) << 3;      // plain swizzled col
  }
  unsigned aoffs[4], boffs[NWC];
#pragma unroll
  for (int g = 0; g < 4; ++g) aoffs[g] = (unsigned)((bm + g * 64 + srow) * AST + colb);
#pragma unroll
  for (int g = 0; g < NWC; ++g) boffs[g] = (unsigned)((bn + g * 64 + srow) * AST + colb);

  // read-side frag offsets (identical address stream in both modes)
  const int arow0 = (wr * (MR * 16) + fm) * 64;
  const int brow0 = (wc * 64 + fm) * 64;
  const int basek0 = (quad * 8) ^ (f7 << 3);       // MODE0: k-half0 | MODE1: hi
  const int basek1 = (32 + quad * 8) ^ (f7 << 3);  // MODE0: k-half1 | MODE1: lo

  f32x4 acc[MR][4];
#pragma unroll
  for (int i = 0; i < MR; ++i)
#pragma unroll
    for (int j = 0; j < 4; ++j) acc[i][j] = (f32x4){0.f, 0.f, 0.f, 0.f};

  // prologue: tiles 0 and 1 in flight
  stageT<NWC>(A, BT, aoffs, boffs, As[0], Bs[0], 0, w);
  stageT<NWC>(A, BT, aoffs, boffs, As[1], Bs[1], KSTEP, w);

#pragma unroll 1
  for (int t = 0; t < NKT; ++t) {
    const unsigned short* Ab = As[t & 1];
    const unsigned short* Bb = Bs[t & 1];
    unsigned short* Asb = As[t & 1];
    unsigned short* Bsb = Bs[t & 1];

    if (t < NKT - 1) {
      if constexpr (NWC == 4) asm volatile("s_waitcnt vmcnt(8)" ::: "memory");
      else                    asm volatile("s_waitcnt vmcnt(6)" ::: "memory");
    } else {
      asm volatile("s_waitcnt vmcnt(0)" ::: "memory");
    }
    __builtin_amdgcn_s_barrier();       // B0: tile t visible to all waves
    __builtin_amdgcn_sched_barrier(0);

    if constexpr (MODE) {
      // ---- split-Markidis 3-term tile: 24 reads, 96 MFMA ----
      bf16x8 bh[4], bl[4];
      bf16x8 ah[2][2], al[2][2];  // [phase parity][row]
#pragma unroll
      for (int j = 0; j < 4; ++j) {
        bh[j] = *(const bf16x8*)&Bb[brow0 + j * 1024 + basek0];
        bl[j] = *(const bf16x8*)&Bb[brow0 + j * 1024 + basek1];
      }
#pragma unroll
      for (int ii = 0; ii < 2; ++ii) {
        ah[0][ii] = *(const bf16x8*)&Ab[arow0 + ii * 1024 + basek0];
        al[0][ii] = *(const bf16x8*)&Ab[arow0 + ii * 1024 + basek1];
      }
      __builtin_amdgcn_sched_barrier(0);

#pragma unroll
      for (int qq = 0; qq < NPH; ++qq) {
        if (qq + 1 < NPH) {
#pragma unroll
          for (int ii = 0; ii < 2; ++ii) {
            ah[(qq + 1) & 1][ii] =
                *(const bf16x8*)&Ab[arow0 + ((qq + 1) * 2 + ii) * 1024 + basek0];
            al[(qq + 1) & 1][ii] =
                *(const bf16x8*)&Ab[arow0 + ((qq + 1) * 2 + ii) * 1024 + basek1];
          }
          asm volatile("s_waitcnt lgkmcnt(4)" ::: "memory");
        } else {
          asm volatile("s_waitcnt lgkmcnt(0)" ::: "memory");
        }
        __builtin_amdgcn_sched_barrier(0);
        __builtin_amdgcn_s_setprio(1);
#pragma unroll
        for (int ii = 0; ii < 2; ++ii)
#pragma unroll
          for (int j = 0; j < 4; ++j) {
            acc[qq * 2 + ii][j] = __builtin_amdgcn_mfma_f32_16x16x32_bf16(
                ah[qq & 1][ii], bh[j], acc[qq * 2 + ii][j], 0, 0, 0);
            acc[qq * 2 + ii][j] = __builtin_amdgcn_mfma_f32_16x16x32_bf16(
                al[qq & 1][ii], bh[j], acc[qq * 2 + ii][j], 0, 0, 0);
            acc[qq * 2 + ii][j] = __builtin_amdgcn_mfma_f32_16x16x32_bf16(
                ah[qq & 1][ii], bl[j], acc[qq * 2 + ii][j], 0, 0, 0);
          }
        __builtin_amdgcn_s_setprio(0);
        __builtin_amdgcn_sched_barrier(0);
      }
    } else {
      // ---- plain bf16 tile (verified round-4 path): 24 reads, 64 MFMA ----
      bf16x8 bfr[4][2];
      bf16x8 afr[2][2][2];  // [phase parity][row][kk]
#pragma unroll
      for (int j = 0; j < 4; ++j) {
        bfr[j][0] = *(const bf16x8*)&Bb[brow0 + j * 1024 + basek0];
        bfr[j][1] = *(const bf16x8*)&Bb[brow0 + j * 1024 + basek1];
      }
#pragma unroll
      for (int ii = 0; ii < 2; ++ii) {
        afr[0][ii][0] = *(const bf16x8*)&Ab[arow0 + ii * 1024 + basek0];
        afr[0][ii][1] = *(const bf16x8*)&Ab[arow0 + ii * 1024 + basek1];
      }
      __builtin_amdgcn_sched_barrier(0);

#pragma unroll
      for (int qq = 0; qq < NPH; ++qq) {
        if (qq + 1 < NPH) {
#pragma unroll
          for (int ii = 0; ii < 2; ++ii) {
            afr[(qq + 1) & 1][ii][0] =
                *(const bf16x8*)&Ab[arow0 + ((qq + 1) * 2 + ii) * 1024 + basek0];
            afr[(qq + 1) & 1][ii][1] =
                *(const bf16x8*)&Ab[arow0 + ((qq + 1) * 2 + ii) * 1024 + basek1];
          }
          asm volatile("s_waitcnt lgkmcnt(4)" ::: "memory");
        } else {
          asm volatile("s_waitcnt lgkmcnt(0)" ::: "memory");
        }
        __builtin_amdgcn_sched_barrier(0);
        __builtin_amdgcn_s_setprio(1);
#pragma unroll
        for (int ii = 0; ii < 2; ++ii)
#pragma unroll
          for (int j = 0; j < 4; ++j) {
            acc[qq * 2 + ii][j] = __builtin_amdgcn_mfma_f32_16x16x32_bf16(
                afr[qq & 1][ii][0], bfr[j][0], acc[qq * 2 + ii][j], 0, 0, 0);
            acc[qq * 2 + ii][j] = __builtin_amdgcn_mfma_f32_16x16x32_bf16(
                afr[qq & 1][ii][1], bfr[j][1], acc[qq * 2 + ii][j], 0, 0, 0);
          }
        __builtin_amdgcn_s_setprio(0);
        __builtin_amdgcn_sched_barrier(0);
      }
    }

    __builtin_amdgcn_s_barrier();       // B1: all waves done reading buf
    if (t + 2 < NKT) {
      stageT<NWC>(A, BT, aoffs, boffs, Asb, Bsb, (t + 2) * KSTEP, w);
    }
  }

  if constexpr (EPI == 0) {
    float* C = (float*)(blockIdx.z ? C1 : C0);
#pragma unroll
    for (int i = 0; i < MR; ++i)
#pragma unroll
      for (int j = 0; j < 4; ++j) {
        size_t row = bm + wr * (MR * 16) + i * 16 + quad * 4;
        size_t col = bn + wc * 64 + j * 16 + fm;
        float bb = bias[col];
#pragma unroll
        for (int r = 0; r < 4; ++r) C[(row + r) * D + col] = acc[i][j][r] + bb;
      }
  } else {
    // softmax over this wave's 64 cols (= one full head), bf16 out
    unsigned short* HB = (unsigned short*)C0;
    const size_t head_col0 = bn + wc * 64;
    float bj[4];
#pragma unroll
    for (int j = 0; j < 4; ++j) bj[j] = bias[head_col0 + j * 16 + fm];
#pragma unroll
    for (int i = 0; i < MR; ++i) {
      f32x4 val[4];
#pragma unroll
      for (int j = 0; j < 4; ++j)
#pragma unroll
        for (int r = 0; r < 4; ++r) val[j][r] = (acc[i][j][r] + bj[j]) * 0.125f;

      f32x4 mx = val[0];
#pragma unroll
      for (int j = 1; j < 4; ++j)
#pragma unroll
        for (int r = 0; r < 4; ++r) mx[r] = fmaxf(mx[r], val[j][r]);
#pragma unroll
      for (int off = 1; off < 16; off <<= 1)
#pragma unroll
        for (int r = 0; r < 4; ++r) mx[r] = fmaxf(mx[r], __shfl_xor(mx[r], off, 64));

      f32x4 e[4];
      f32x4 sm = (f32x4){0.f, 0.f, 0.f, 0.f};
#pragma unroll
      for (int j = 0; j < 4; ++j)
#pragma unroll
        for (int r = 0; r < 4; ++r) {
          e[j][r] = __expf(val[j][r] - mx[r]);
          sm[r] += e[j][r];
        }
#pragma unroll
      for (int off = 1; off < 16; off <<= 1)
#pragma unroll
        for (int r = 0; r < 4; ++r) sm[r] += __shfl_xor(sm[r], off, 64);

      f32x4 inv;
#pragma unroll
      for (int r = 0; r < 4; ++r) inv[r] = 1.0f / sm[r];

#pragma unroll
      for (int j = 0; j < 4; ++j)
#pragma unroll
        for (int r = 0; r < 4; ++r) {
          size_t row = bm + wr * (MR * 16) + i * 16 + quad * 4 + r;
          HB[row * D + head_col0 + j * 16 + fm] = f2bf(e[j][r] * inv[r]);
        }
    }
  }
}

// ---------------------------------------------------------------------------
// M[b,h] = kh^T @ vh (64x64 per (b,h)), s-split 8-way with atomics.
// ---------------------------------------------------------------------------
__global__ __launch_bounds__(256) void compute_m_kernel(
    const float* __restrict__ KH, const float* __restrict__ VH, float* __restrict__ Mout) {
  const int sc = blockIdx.x, h = blockIdx.y, b = blockIdx.z;
  const int tid = threadIdx.x;
  const int i0 = (tid >> 4) * 4;
  const int j0 = (tid & 15) * 4;
  __shared__ float ks[16][64], vs[16][64];
  float acc[4][4];
#pragma unroll
  for (int a = 0; a < 4; a++)
#pragma unroll
    for (int c = 0; c < 4; c++) acc[a][c] = 0.f;

  const int s0 = sc * (S / 8);
  const int rr = tid >> 4;
  const int cc = (tid & 15) * 4;
  for (int s = s0; s < s0 + S / 8; s += 16) {
    size_t base = ((size_t)b * S + s + rr) * D + h * 64 + cc;
    __syncthreads();
    *(float4*)&ks[rr][cc] = *(const float4*)&KH[base];
    *(float4*)&vs[rr][cc] = *(const float4*)&VH[base];
    __syncthreads();
#pragma unroll
    for (int ss = 0; ss < 16; ss++) {
      float4 kf = *(const float4*)&ks[ss][i0];
      float4 vf = *(const float4*)&vs[ss][j0];
      float ka[4] = {kf.x, kf.y, kf.z, kf.w};
      float va[4] = {vf.x, vf.y, vf.z, vf.w};
#pragma unroll
      for (int a = 0; a < 4; a++)
#pragma unroll
        for (int c = 0; c < 4; c++) acc[a][c] += ka[a] * va[c];
    }
  }
  float* Mp = Mout + ((size_t)(b * H + h)) * DK * DK;
#pragma unroll
  for (int a = 0; a < 4; a++)
#pragma unroll
    for (int c = 0; c < 4; c++) atomicAdd(&Mp[(i0 + a) * DK + j0 + c], acc[a][c]);
}

// ---------------------------------------------------------------------------
// split_m_bias: M fp32 [bh][64k][64n] -> MSP bf16 [bh][2][64n][64k] (transposed
// hi,lo) AND BQM[bh][64 j] = sum_k bq[h,k]*M[k,j]  (unscaled).
// ---------------------------------------------------------------------------
__global__ __launch_bounds__(256) void split_m_bias_kernel(
    const float* __restrict__ M, const float* __restrict__ bq,
    unsigned short* __restrict__ MSP, float* __restrict__ BQM) {
  const int bh = blockIdx.x;
  const int h = bh & 15;
  const float* Mp = M + (size_t)bh * 4096;
  unsigned short* hiP = MSP + (size_t)bh * 8192;
  unsigned short* loP = hiP + 4096;
  for (int idx = threadIdx.x; idx < 4096; idx += 256) {
    int kk = idx >> 6, nn = idx & 63;
    unsigned short hi, lo;
    split2(Mp[idx], hi, lo);
    hiP[nn * 64 + kk] = hi;
    loP[nn * 64 + kk] = lo;
  }
  if (threadIdx.x < 64) {
    int j = threadIdx.x;
    float a = 0.f;
#pragma unroll 8
    for (int kk = 0; kk < 64; kk++) a += bq[h * 64 + kk] * Mp[kk * 64 + j];
    BQM[(size_t)bh * 64 + j] = a;
  }
}

// ---------------------------------------------------------------------------
// wqm: Wq'[b,h] = Wq[h] @ M[b,h]  (1024x64 per pair), 3-term split MFMA.
// A = WQA [h][1024 d][hi64|lo64]; B = MSP [bh][2][64 n][64 k] (transposed).
// Output WQM [b][n=h*64+j][d hi | 1024+d lo] (B^T layout for the qsm GEMM).
// grid (16, H, B); block = 64 d-rows; wave w owns d-rows [c*64+w*16, +16).
// ---------------------------------------------------------------------------
__global__ __launch_bounds__(256) void wqm_kernel(
    const unsigned short* __restrict__ WQA, const unsigned short* __restrict__ MSP,
    unsigned short* __restrict__ WQM) {
  const int c = blockIdx.x, h = blockIdx.y, b = blockIdx.z;
  const int tid = threadIdx.x;
  const int lane = tid & 63;
  const int w = tid >> 6;
  const int fm = lane & 15;
  const int quad = lane >> 4;
  const int ko = quad * 8;
  const int dbase = c * 64 + w * 16;

  const unsigned short* arow = WQA + ((size_t)h * 1024 + dbase + fm) * 128;
  bf16x8 ahi0 = *(const bf16x8*)&arow[ko];        // k 0..31 hi
  bf16x8 ahi1 = *(const bf16x8*)&arow[32 + ko];   // k 32..63 hi
  bf16x8 alo0 = *(const bf16x8*)&arow[64 + ko];   // k 0..31 lo
  bf16x8 alo1 = *(const bf16x8*)&arow[96 + ko];   // k 32..63 lo

  const unsigned short* hiP = MSP + ((size_t)(b * H + h)) * 8192;
  const unsigned short* loP = hiP + 4096;
  f32x4 acc[4];
#pragma unroll
  for (int j = 0; j < 4; j++) acc[j] = (f32x4){0.f, 0.f, 0.f, 0.f};
#pragma unroll
  for (int j = 0; j < 4; j++) {
    bf16x8 bhi0 = *(const bf16x8*)&hiP[(j * 16 + fm) * 64 + ko];
    bf16x8 bhi1 = *(const bf16x8*)&hiP[(j * 16 + fm) * 64 + 32 + ko];
    bf16x8 blo0 = *(const bf16x8*)&loP[(j * 16 + fm) * 64 + ko];
    bf16x8 blo1 = *(const bf16x8*)&loP[(j * 16 + fm) * 64 + 32 + ko];
    acc[j] = __builtin_amdgcn_mfma_f32_16x16x32_bf16(ahi0, bhi0, acc[j], 0, 0, 0);
    acc[j] = __builtin_amdgcn_mfma_f32_16x16x32_bf16(ahi1, bhi1, acc[j], 0, 0, 0);
    acc[j] = __builtin_amdgcn_mfma_f32_16x16x32_bf16(alo0, bhi0, acc[j], 0, 0, 0);
    acc[j] = __builtin_amdgcn_mfma_f32_16x16x32_bf16(alo1, bhi1, acc[j], 0, 0, 0);
    acc[j] = __builtin_amdgcn_mfma_f32_16x16x32_bf16(ahi0, blo0, acc[j], 0, 0, 0);
    acc[j] = __builtin_amdgcn_mfma_f32_16x16x32_bf16(ahi1, blo1, acc[j], 0, 0, 0);
  }

  // C[d=dbase+quad*4+r][col j*16+fm]; write split to WQM[b][h*64+col][d]
#pragma unroll
  for (int j = 0; j < 4; j++) {
    int n = h * 64 + j * 16 + fm;
    ushort4 hv, lv;
    unsigned short hi, lo;
    split2(acc[j][0], hi, lo); hv.x = hi; lv.x = lo;
    split2(acc[j][1], hi, lo); hv.y = hi; lv.y = lo;
    split2(acc[j][2], hi, lo); hv.z = hi; lv.z = lo;
    split2(acc[j][3], hi, lo); hv.w = hi; lv.w = lo;
    size_t base = ((size_t)b * D + n) * GKA + dbase + quad * 4;
    *(ushort4*)&WQM[base] = hv;
    *(ushort4*)&WQM[base + 1024] = lv;
  }
}

// ---------------------------------------------------------------------------
extern "C" void kernel_launch(void* const* d_in, const int* in_sizes, int n_in,
                              void* d_out, int out_size, void* d_ws, size_t ws_size,
                              hipStream_t stream) {
  const float* q = (const float*)d_in[0];
  const float* k = (const float*)d_in[1];
  const float* v = (const float*)d_in[2];
  const float* wq_w = (const float*)d_in[3];
  const float* wq_b = (const float*)d_in[4];
  const float* wk_w = (const float*)d_in[5];
  const float* wk_b = (const float*)d_in[6];
  const float* wv_w = (const float*)d_in[7];
  const float* wv_b = (const float*)d_in[8];
  const float* wo_w = (const float*)d_in[9];
  const float* wo_b = (const float*)d_in[10];
  float* out = (float*)d_out;

  // ws (143 MB): KSP 32 (->HB 16 | WQM 16) | VSP 32 (->MSP 1 + BQM) | QSP 32 |
  //              VH 32 | M 1 | WKS 4 | WVS 4 | WQA 4 | WOB 2.   KH lives in d_out.
  unsigned short* KSP = (unsigned short*)d_ws;
  unsigned short* VSP = KSP + (size_t)16 * 1024 * 1024;
  unsigned short* QSP = VSP + (size_t)16 * 1024 * 1024;
  float* VH = (float*)(QSP + (size_t)16 * 1024 * 1024);
  float* M = VH + (size_t)MS * D;
  unsigned short* WKS = (unsigned short*)(M + 256 * 1024);
  unsigned short* WVS = WKS + (size_t)2 * 1024 * 1024;
  unsigned short* WQA = WVS + (size_t)2 * 1024 * 1024;
  unsigned short* WOB = WQA + (size_t)2 * 1024 * 1024;
  // aliases
  float* KH = out;                                   // dead after compute_m
  unsigned short* HB = KSP;                          // KSP dead after gemm KV
  unsigned short* WQM = KSP + (size_t)8 * 1024 * 1024;
  unsigned short* MSP = VSP;                         // VSP dead after gemm KV
  float* BQM = (float*)(VSP + 512 * 1024);

  dim3 blk(256);

  prep_kernel<<<38144, blk, 0, stream>>>(q, k, v, wk_w, wv_w, wq_w, wo_w,
                                         KSP, VSP, QSP, WKS, WVS, WQA, WOB, M);
  // K/V projections: 256x256 tiles, split-Markidis 3-term (MODE 1)
  gemm256<4, 0, 1><<<dim3(4, 32, 2), dim3(512), 0, stream>>>(
      KSP, VSP, WKS, WVS, wk_b, wv_b, KH, VH);
  compute_m_kernel<<<dim3(8, H, B), blk, 0, stream>>>(KH, VH, M);
  split_m_bias_kernel<<<64, blk, 0, stream>>>(M, wq_b, MSP, BQM);
  wqm_kernel<<<dim3(16, H, B), blk, 0, stream>>>(WQA, MSP, WQM);
  // fused logit GEMM + softmax: 256x128 tiles, split 3-term (MODE 1)
  gemm256<2, 1, 1><<<dim3(8, 32, 1), dim3(512), 0, stream>>>(
      QSP, nullptr, WQM, nullptr, BQM, nullptr, HB, nullptr);
  // output projection: plain bf16, K=1024 (MODE 0, verified path)
  gemm256<2, 0, 0><<<dim3(8, 32, 1), dim3(512), 0, stream>>>(
      HB, HB, WOB, WOB, wo_b, wo_b, out, out);
}